// Round 8
// baseline (31833.267 us; speedup 1.0000x reference)
//
#include <hip/hip_runtime.h>
#include <cstdint>
#include <cstddef>

// ---------------- types ----------------
typedef __bf16 bf16;
typedef __bf16 bf16x8 __attribute__((ext_vector_type(8)));
typedef float  f32x4  __attribute__((ext_vector_type(4)));
typedef unsigned int uint2v __attribute__((ext_vector_type(2)));
typedef unsigned int uint4v __attribute__((ext_vector_type(4)));
typedef unsigned long long u64;

// ---------------- problem sizes ----------------
constexpr int B_=256, T_=512, H_=512, X_=128, S_=64, IN0=192;
constexpr int NG=2;              // batch groups
constexpr int MG=128;            // rows per group
constexpr int WPG=128;           // workgroups per group (slices)
constexpr int KB_X=4, KB_H=16, KB_S=2;

// ---------------- ws layout ----------------
constexpr size_t OFF_FLG=0;                           // 2*128*64 = 16384 B
constexpr size_t OFF_BC =16384;                       // 2*64 B (pad to 32768)
constexpr size_t OFF_SC =32768;                       // [2][NG][64][128] f32 = 131072 B
constexpr size_t OFF_HP =OFF_SC+2ull*NG*64*128*4;     // 4 planes: H0H,H0L,H1H,H1L
constexpr size_t PLANE  =2ull*B_*H_*2;                // 524288 B each (double buffered)
constexpr size_t WS_NEED=OFF_HP+4*PLANE;              // ~2.3 MB

// ---------------- LDS ----------------
constexpr int NWX=KB_X*512;
constexpr int NWH=KB_H*512;
constexpr int NWS=KB_S*512;
constexpr int SMEM_BYTES = (2*NWX + 8*NWH + 2*NWS)*2
                         + 512*4 + 128*17*4 + 512*2*2 + 32*4;
static_assert(SMEM_BYTES == 156288, "lds size");
static_assert(SMEM_BYTES <= 160*1024, "lds limit");

// ---------------- access helpers ----------------
// Panel reads are now NORMAL CACHED loads (L2-allocating). Coherence is
// provided by buffer_inv sc1 executed inside every group barrier: panels are
// written sc1 (write-through, never dirty in L2), so invalidate-only is
// sufficient AND cheap (no writeback walk). 32 CUs/XCD share one L3 fill.
__device__ __forceinline__ uint4v ald16(const bf16* p) {
  uint4v r;
  asm volatile("global_load_dwordx4 %0, %1, off"
               : "=&v"(r) : "v"(p) : "memory");
  return r;
}
__device__ __forceinline__ bf16x8 MK4(uint4v q) {
  union { uint4v q; bf16x8 v; } u; u.q = q;
  return u.v;
}
__device__ __forceinline__ void astore8(bf16* p, uint2v v) {
  union { uint2v v; u64 q; } u; u.v = v;
  __hip_atomic_store((u64*)p, u.q, __ATOMIC_RELAXED, __HIP_MEMORY_SCOPE_AGENT);
}
__device__ __forceinline__ void astoref(float* p, float v) {
  __hip_atomic_store((unsigned*)p, __float_as_uint(v), __ATOMIC_RELAXED, __HIP_MEMORY_SCOPE_AGENT);
}
__device__ __forceinline__ float aloadf(const float* p) {
  return __uint_as_float(__hip_atomic_load((unsigned*)p, __ATOMIC_RELAXED, __HIP_MEMORY_SCOPE_AGENT));
}

// ---------------- helpers ----------------
__device__ __forceinline__ f32x4 mfma16(bf16x8 a, bf16x8 b, f32x4 c) {
  return __builtin_amdgcn_mfma_f32_16x16x32_bf16(a, b, c, 0, 0, 0);
}
__device__ __forceinline__ f32x4 mfma3(bf16x8 ah, bf16x8 al, bf16x8 wh, bf16x8 wl, f32x4 c) {
  c = mfma16(ah, wh, c);
  c = mfma16(al, wh, c);
  c = mfma16(ah, wl, c);
  return c;
}
__device__ __forceinline__ void split8p(const float* v, bf16x8& ah, bf16x8& al) {
  #pragma unroll
  for (int i=0;i<8;++i){ float f=v[i]; bf16 h=(bf16)f; ah[i]=h; al[i]=(bf16)(f-(float)h); }
}
__device__ __forceinline__ void split8v(f32x4 v0, f32x4 v1, bf16x8& ah, bf16x8& al) {
  #pragma unroll
  for (int i=0;i<4;++i){ float f=v0[i]; bf16 h=(bf16)f; ah[i]=h; al[i]=(bf16)(f-(float)h); }
  #pragma unroll
  for (int i=0;i<4;++i){ float f=v1[i]; bf16 h=(bf16)f; ah[4+i]=h; al[4+i]=(bf16)(f-(float)h); }
}
__device__ __forceinline__ float sigm(float v) { return 1.0f / (1.0f + __expf(-v)); }
__device__ __forceinline__ float tanhr(float v) {
  v = fminf(15.0f, fmaxf(-15.0f, v));
  float e = __expf(2.0f * v);
  return (e - 1.0f) / (e + 1.0f);
}

// Fence-free group barrier + cache invalidate.
// buffer_inv sc1 AFTER the broadcast: flash-invalidates (clean) L1/L2 panel
// lines so post-barrier cached reads see the sc1-written fresh data in L3.
__device__ __forceinline__ void group_barrier(int* flg, int* bc, int ns, int& phase) {
  ++phase;
  const int p = phase;
  asm volatile("s_waitcnt vmcnt(0)" ::: "memory");
  __syncthreads();
  if (threadIdx.x == 0)
    __hip_atomic_store(flg + ns*16, p, __ATOMIC_RELAXED, __HIP_MEMORY_SCOPE_AGENT);
  if (ns == 0) {
    if (threadIdx.x < WPG) {
      while (__hip_atomic_load(flg + (int)threadIdx.x*16, __ATOMIC_RELAXED,
                               __HIP_MEMORY_SCOPE_AGENT) < p)
        __builtin_amdgcn_s_sleep(1);
    }
    __syncthreads();
    if (threadIdx.x == 0)
      __hip_atomic_store(bc, p, __ATOMIC_RELAXED, __HIP_MEMORY_SCOPE_AGENT);
  }
  if (threadIdx.x == 0) {
    while (__hip_atomic_load(bc, __ATOMIC_RELAXED, __HIP_MEMORY_SCOPE_AGENT) < p)
      __builtin_amdgcn_s_sleep(1);
  }
  __syncthreads();
  asm volatile("buffer_inv sc1" ::: "memory");   // drop stale clean L1/L2 lines
  __builtin_amdgcn_sched_barrier(0);
}

__device__ void pack_slice(bf16* dH, bf16* dL, const float* src, int stride,
                           int koff, int nkb, int ns) {
  for (int p = (int)threadIdx.x; p < nkb*64; p += 256) {
    int ln = p & 63, kb = p >> 6;
    int c = ln & 15, k = kb*32 + ((ln>>4)<<3);
    int gcol = ((c>>2)<<9) + ns*4 + (c&3);
    const float* sp = src + (size_t)gcol*stride + koff + k;
    f32x4 v0 = *(const f32x4*)sp, v1 = *(const f32x4*)(sp+4);
    bf16x8 hv, lv;
    split8v(v0, v1, hv, lv);
    *(bf16x8*)(dH + p*8) = hv;
    *(bf16x8*)(dL + p*8) = lv;
  }
}

// ---------------- zero kernel (sc1 write-through so L3 is authoritative) ----
__global__ void zero_kernel(char* __restrict__ ws) {
  size_t i = (size_t)blockIdx.x*256 + threadIdx.x;
  size_t nsync = 32768/8;
  if (i < nsync) {
    __hip_atomic_store((u64*)(ws+OFF_FLG) + i, 0ull,
                       __ATOMIC_RELAXED, __HIP_MEMORY_SCOPE_AGENT);
    return;
  }
  i -= nsync;
  if (i < 4*PLANE/8)
    __hip_atomic_store((u64*)(ws+OFF_HP) + i, 0ull,
                       __ATOMIC_RELAXED, __HIP_MEMORY_SCOPE_AGENT);
}

// ---------------- persistent LSTM kernel ----------------
#define FRL(base, kb) (*(const bf16x8*)((base) + (((kb)*64 + lane)*8)))

// Batched half-chain: issue 32 x 16B cached loads (2 mt x 8 kb x {hi,lo}),
// waitcnt + sched_barrier, then consume with MFMAs.
template<bool DUAL>
__device__ __forceinline__ void chain8(const bf16* pH, const bf16* pL,
    const bf16* sWH, const bf16* sWL, const bf16* sW2H, const bf16* sW2L,
    int lane, const int* rowA, int kq, int kb0, f32x4* accA, f32x4* accB)
{
  uint4v qh[2][8], ql[2][8];
  #pragma unroll
  for (int mt=0;mt<2;++mt) {
    const bf16* bH = pH + (size_t)rowA[mt]*H_ + kb0*32 + kq;
    const bf16* bL = pL + (size_t)rowA[mt]*H_ + kb0*32 + kq;
    #pragma unroll
    for (int k=0;k<8;++k) {
      qh[mt][k] = ald16(bH + k*32);
      ql[mt][k] = ald16(bL + k*32);
    }
  }
  asm volatile("s_waitcnt vmcnt(0)" ::: "memory");
  __builtin_amdgcn_sched_barrier(0);
  #pragma unroll
  for (int k=0;k<8;++k) {
    const int kb = kb0 + k;
    bf16x8 wh = FRL(sWH,kb), wl = FRL(sWL,kb);
    #pragma unroll
    for (int mt=0;mt<2;++mt) {
      bf16x8 ah = MK4(qh[mt][k]), al2 = MK4(ql[mt][k]);
      accA[mt] = mfma3(ah, al2, wh, wl, accA[mt]);
      if (DUAL) {
        bf16x8 w2h = FRL(sW2H,kb), w2l = FRL(sW2L,kb);
        accB[mt] = mfma3(ah, al2, w2h, w2l, accB[mt]);
      }
    }
  }
}

// fc half-row dot: 32 x 16B cached loads then fp32 dot with LDS weights
__device__ __forceinline__ float fc_half(const bf16* hH, const bf16* hL,
                                         const float* wp)
{
  float a = 0.f;
  #pragma unroll
  for (int half = 0; half < 2; ++half) {
    uint4v qh[16], ql[16];
    #pragma unroll
    for (int c2 = 0; c2 < 16; ++c2) {
      qh[c2] = ald16(hH + half*128 + c2*8);
      ql[c2] = ald16(hL + half*128 + c2*8);
    }
    asm volatile("s_waitcnt vmcnt(0)" ::: "memory");
    __builtin_amdgcn_sched_barrier(0);
    #pragma unroll
    for (int c2 = 0; c2 < 16; ++c2) {
      bf16x8 hv = MK4(qh[c2]), lv = MK4(ql[c2]);
      const float* w2 = wp + half*128 + c2*8;
      f32x4 w0 = *(const f32x4*)w2, w1 = *(const f32x4*)(w2+4);
      a += ((float)hv[0]+(float)lv[0])*w0[0] + ((float)hv[1]+(float)lv[1])*w0[1]
         + ((float)hv[2]+(float)lv[2])*w0[2] + ((float)hv[3]+(float)lv[3])*w0[3]
         + ((float)hv[4]+(float)lv[4])*w1[0] + ((float)hv[5]+(float)lv[5])*w1[1]
         + ((float)hv[6]+(float)lv[6])*w1[2] + ((float)hv[7]+(float)lv[7])*w1[3];
    }
  }
  return a;
}

__global__ void __launch_bounds__(256, 1)
lstm_kernel(const float* __restrict__ x, const float* __restrict__ s0,
            const float* __restrict__ Wi0, const float* __restrict__ Wh0g,
            const float* __restrict__ bi0, const float* __restrict__ bh0,
            const float* __restrict__ Wi1g, const float* __restrict__ Wh1g,
            const float* __restrict__ bi1, const float* __restrict__ bh1,
            const float* __restrict__ Wfc, const float* __restrict__ bfc,
            float* __restrict__ out, char* __restrict__ ws)
{
  const int bid = blockIdx.x;
  const int g = bid & 1, ns = bid >> 1;
  const int tid = threadIdx.x;
  const int w = tid >> 6, lane = tid & 63, l15 = lane & 15;
  const int kq = (lane >> 4) << 3;
  const int mB = g * MG;
  int rowA[2];
  rowA[0] = mB + (w*2)*16 + l15;
  rowA[1] = rowA[0] + 16;

  int* flg = (int*)(ws + OFF_FLG) + g*128*16;
  int* bc  = (int*)(ws + OFF_BC) + g*16;
  float* SCbase = (float*)(ws + OFF_SC);
  bf16* H0H_ = (bf16*)(ws + OFF_HP);
  bf16* H0L_ = (bf16*)(ws + OFF_HP + PLANE);
  bf16* H1H_ = (bf16*)(ws + OFF_HP + 2*PLANE);
  bf16* H1L_ = (bf16*)(ws + OFF_HP + 3*PLANE);

  extern __shared__ char smem[];
  bf16* sWxH  = (bf16*)smem;
  bf16* sWxL  = sWxH + NWX;
  bf16* sWh0H = sWxL + NWX;
  bf16* sWh0L = sWh0H + NWH;
  bf16* sWcbH = sWh0L + NWH;
  bf16* sWcbL = sWcbH + NWH;
  bf16* sWi1H = sWcbL + NWH;
  bf16* sWi1L = sWi1H + NWH;
  bf16* sWh1H = sWi1L + NWH;
  bf16* sWh1L = sWh1H + NWH;
  bf16* sWsH  = sWh1L + NWH;
  bf16* sWsL  = sWsH + NWS;
  float* sWfc = (float*)(sWsL + NWS);
  float* sG   = sWfc + 512;
  bf16*  sHh  = (bf16*)(sG + 128*17);
  bf16*  sHl  = sHh + 512;
  float* sB0  = (float*)(sHl + 512);
  float* sB1  = sB0 + 16;

  // ---- in-kernel weight packing (hi/lo bf16 pairs) ----
  pack_slice(sWxH,  sWxL,  Wi0,  IN0, 0,  KB_X, ns);
  pack_slice(sWh0H, sWh0L, Wh0g, H_,  0,  KB_H, ns);
  pack_slice(sWi1H, sWi1L, Wi1g, H_,  0,  KB_H, ns);
  pack_slice(sWh1H, sWh1L, Wh1g, H_,  0,  KB_H, ns);
  pack_slice(sWsH,  sWsL,  Wi0,  IN0, X_, KB_S, ns);
  for (int p = tid; p < KB_H*64; p += 256) {
    int ln = p & 63, kb = p >> 6;
    int c = ln & 15, k = kb*32 + ((ln>>4)<<3);
    int gcol = ((c>>2)<<9) + ns*4 + (c&3);
    const float* wis = Wi0 + (size_t)gcol*IN0 + X_;
    float a[8] = {0,0,0,0,0,0,0,0};
    for (int o = 0; o < S_; ++o) {
      float wv = wis[o];
      const float* fr = Wfc + (size_t)o*H_ + k;
      f32x4 f0 = *(const f32x4*)fr, f1 = *(const f32x4*)(fr+4);
      a[0]+=wv*f0[0]; a[1]+=wv*f0[1]; a[2]+=wv*f0[2]; a[3]+=wv*f0[3];
      a[4]+=wv*f1[0]; a[5]+=wv*f1[1]; a[6]+=wv*f1[2]; a[7]+=wv*f1[3];
    }
    bf16x8 hv, lv;
    split8p(a, hv, lv);
    *(bf16x8*)(sWcbH + p*8) = hv;
    *(bf16x8*)(sWcbL + p*8) = lv;
  }
  for (int j = tid; j < H_; j += 256) sWfc[j] = Wfc[(size_t)(ns>>1)*H_ + j];
  if (tid < 16) {
    int gcol = ((tid>>2)<<9) + ns*4 + (tid&3);
    sB0[tid] = bi0[gcol] + bh0[gcol];
    sB1[tid] = bi1[gcol] + bh1[gcol];
  }

  float bfcW;
  {
    int gcol = ((l15>>2)<<9) + ns*4 + (l15&3);
    const float* wr = Wi0 + (size_t)gcol*IN0 + X_;
    float bw = 0.f;
    for (int o = 0; o < S_; ++o) bw += bfc[o]*wr[o];
    bfcW = bw;
  }
  const float bfc_ns = bfc[ns>>1];

  float s_reg[2][16];
  #pragma unroll
  for (int mt=0;mt<2;++mt)
    #pragma unroll
    for (int kb=0;kb<KB_S;++kb)
      #pragma unroll
      for (int i=0;i<8;++i)
        s_reg[mt][kb*8+i] = s0[(size_t)rowA[mt]*S_ + kb*32 + kq + i];

  __syncthreads();

  f32x4 Gs[2];
  #pragma unroll
  for (int mt=0;mt<2;++mt) {
    bf16x8 sh0,sl0,sh1,sl1;
    split8p(&s_reg[mt][0], sh0, sl0);
    split8p(&s_reg[mt][8], sh1, sl1);
    f32x4 a = (f32x4){0.f,0.f,0.f,0.f};
    a = mfma3(sh0, sl0, FRL(sWsH,0), FRL(sWsL,0), a);
    a = mfma3(sh1, sl1, FRL(sWsH,1), FRL(sWsL,1), a);
    Gs[mt] = a;
  }

  float c0s[2] = {0.f,0.f}, c1s[2] = {0.f,0.f};
  const int crow = tid >> 1;
  const int dbase = (tid & 1) << 1;
  const int frow = tid >> 1, fhalf = tid & 1;
  int phase = 0;

  for (int t = 0; t < T_; ++t) {
    const int rd = t & 1, wr = rd ^ 1;
    const size_t rdo = (size_t)rd*B_*H_, wro = (size_t)wr*B_*H_;
    float* SCp = SCbase + ((size_t)rd*NG + g)*(64*128);

    // ---- fc (fp32, even slices): out(t-1)[:, ns>>1] ----
    if (t > 0 && (ns & 1) == 0) {
      const bf16* hH = H1H_ + rdo + (size_t)(mB+frow)*H_ + fhalf*256;
      const bf16* hL = H1L_ + rdo + (size_t)(mB+frow)*H_ + fhalf*256;
      float a = fc_half(hH, hL, sWfc + fhalf*256);
      a += __shfl_xor(a, 1);
      if (fhalf == 0) {
        float o = a + bfc_ns;
        out[((size_t)(mB+frow)*T_ + (t-1))*S_ + (ns>>1)] = o;
        astoref(&SCp[(ns>>1)*128 + frow], o);
      }
    }

    // ---- phase-1 MFMA ----
    f32x4 acc0[2], acc1[2];
    {
      float addb = (t > 0) ? bfcW : 0.f;
      #pragma unroll
      for (int mt=0;mt<2;++mt) {
        #pragma unroll
        for (int r=0;r<4;++r) acc0[mt][r] = Gs[mt][r] + addb;
        acc1[mt] = (f32x4){0.f,0.f,0.f,0.f};
      }
    }
    #pragma unroll
    for (int kb=0; kb<KB_X; ++kb) {          // x chain (cached loads)
      bf16x8 wh = FRL(sWxH,kb), wl = FRL(sWxL,kb);
      #pragma unroll
      for (int mt=0;mt<2;++mt) {
        const float* xp = x + ((size_t)rowA[mt]*T_ + t)*X_ + kb*32 + kq;
        bf16x8 ah, al2;
        split8v(*(const f32x4*)xp, *(const f32x4*)(xp+4), ah, al2);
        acc0[mt] = mfma3(ah, al2, wh, wl, acc0[mt]);
      }
    }
    // h1(t-1): shared A feeds Wcb (acc0) + Wh1 (acc1)
    chain8<true>(H1H_+rdo, H1L_+rdo, sWcbH, sWcbL, sWh1H, sWh1L, lane, rowA, kq, 0, acc0, acc1);
    chain8<true>(H1H_+rdo, H1L_+rdo, sWcbH, sWcbL, sWh1H, sWh1L, lane, rowA, kq, 8, acc0, acc1);
    // h0(t-1): acc0
    chain8<false>(H0H_+rdo, H0L_+rdo, sWh0H, sWh0L, sWh0H, sWh0L, lane, rowA, kq, 0, acc0, acc1);
    chain8<false>(H0H_+rdo, H0L_+rdo, sWh0H, sWh0L, sWh0H, sWh0L, lane, rowA, kq, 8, acc0, acc1);

    // bounce C -> (row, gatecol)
    #pragma unroll
    for (int mt=0;mt<2;++mt)
      #pragma unroll
      for (int r=0;r<4;++r)
        sG[((w*2+mt)*16 + ((lane>>4)<<2) + r)*17 + l15] = acc0[mt][r];
    __syncthreads();
    {   // cell 0
      const float* gr = sG + crow*17;
      #pragma unroll
      for (int j=0;j<2;++j) {
        int d = dbase + j;
        float gi = gr[d]    + sB0[d];
        float gf = gr[4+d]  + sB0[4+d];
        float gg = gr[8+d]  + sB0[8+d];
        float go = gr[12+d] + sB0[12+d];
        c0s[j] = sigm(gf)*c0s[j] + sigm(gi)*tanhr(gg);
        float h = sigm(go)*tanhr(c0s[j]);
        bf16 hh = (bf16)h;
        sHh[crow*4+d] = hh;
        sHl[crow*4+d] = (bf16)(h - (float)hh);
      }
    }
    __syncthreads();
    if (tid < MG) {
      size_t off = wro + (size_t)(mB+tid)*H_ + ns*4;
      astore8(H0H_ + off, *(const uint2v*)(sHh + tid*4));
      astore8(H0L_ + off, *(const uint2v*)(sHl + tid*4));
    }
    group_barrier(flg, bc, ns, phase);   // A: h0(t) + out columns visible

    // ---- s(t) = s(t-1) + out(t-1); fresh Gs ----
    if (t > 0) {
      const float* SCr = SCbase + ((size_t)rd*NG + g)*(64*128);
      #pragma unroll
      for (int mt=0;mt<2;++mt) {
        int rloc = (w*2+mt)*16 + l15;
        #pragma unroll
        for (int kb=0;kb<KB_S;++kb)
          #pragma unroll
          for (int i=0;i<8;++i)
            s_reg[mt][kb*8+i] += aloadf(&SCr[(kb*32+kq+i)*128 + rloc]);
      }
    }
    #pragma unroll
    for (int mt=0;mt<2;++mt) {
      bf16x8 sh0,sl0,sh1,sl1;
      split8p(&s_reg[mt][0], sh0, sl0);
      split8p(&s_reg[mt][8], sh1, sl1);
      f32x4 a = (f32x4){0.f,0.f,0.f,0.f};
      a = mfma3(sh0, sl0, FRL(sWsH,0), FRL(sWsL,0), a);
      a = mfma3(sh1, sl1, FRL(sWsH,1), FRL(sWsL,1), a);
      Gs[mt] = a;
    }

    // ---- layer 1: acc1 += h0(t).Wi1 ----
    chain8<false>(H0H_+wro, H0L_+wro, sWi1H, sWi1L, sWi1H, sWi1L, lane, rowA, kq, 0, acc1, acc0);
    chain8<false>(H0H_+wro, H0L_+wro, sWi1H, sWi1L, sWi1H, sWi1L, lane, rowA, kq, 8, acc1, acc0);

    #pragma unroll
    for (int mt=0;mt<2;++mt)
      #pragma unroll
      for (int r=0;r<4;++r)
        sG[((w*2+mt)*16 + ((lane>>4)<<2) + r)*17 + l15] = acc1[mt][r];
    __syncthreads();
    {   // cell 1
      const float* gr = sG + crow*17;
      #pragma unroll
      for (int j=0;j<2;++j) {
        int d = dbase + j;
        float gi = gr[d]    + sB1[d];
        float gf = gr[4+d]  + sB1[4+d];
        float gg = gr[8+d]  + sB1[8+d];
        float go = gr[12+d] + sB1[12+d];
        c1s[j] = sigm(gf)*c1s[j] + sigm(gi)*tanhr(gg);
        float h = sigm(go)*tanhr(c1s[j]);
        bf16 hh = (bf16)h;
        sHh[crow*4+d] = hh;
        sHl[crow*4+d] = (bf16)(h - (float)hh);
      }
    }
    __syncthreads();
    if (tid < MG) {
      size_t off = wro + (size_t)(mB+tid)*H_ + ns*4;
      astore8(H1H_ + off, *(const uint2v*)(sHh + tid*4));
      astore8(H1L_ + off, *(const uint2v*)(sHl + tid*4));
    }
    group_barrier(flg, bc, ns, phase);   // B: h1(t) visible
  }

  // ---- epilogue: out(T-1) ----
  if ((ns & 1) == 0) {
    const bf16* hH = H1H_ + (size_t)(mB+frow)*H_ + fhalf*256;
    const bf16* hL = H1L_ + (size_t)(mB+frow)*H_ + fhalf*256;
    float a = fc_half(hH, hL, sWfc + fhalf*256);
    a += __shfl_xor(a, 1);
    if (fhalf == 0)
      out[((size_t)(mB+frow)*T_ + (T_-1))*S_ + (ns>>1)] = a + bfc_ns;
  }
}

// ---------------- launcher ----------------
extern "C" void kernel_launch(void* const* d_in, const int* in_sizes, int n_in,
                              void* d_out, int out_size, void* d_ws, size_t ws_size,
                              hipStream_t stream)
{
  const float* x   = (const float*)d_in[0];
  const float* s0  = (const float*)d_in[1];
  const float* Wi0 = (const float*)d_in[2];
  const float* Wh0 = (const float*)d_in[3];
  const float* bi0 = (const float*)d_in[4];
  const float* bh0 = (const float*)d_in[5];
  const float* Wi1 = (const float*)d_in[6];
  const float* Wh1 = (const float*)d_in[7];
  const float* bi1 = (const float*)d_in[8];
  const float* bh1 = (const float*)d_in[9];
  const float* Wfc = (const float*)d_in[10];
  const float* bfc = (const float*)d_in[11];
  float* out = (float*)d_out;
  char* ws = (char*)d_ws;

  if (ws_size < WS_NEED) return;

  hipFuncSetAttribute(reinterpret_cast<const void*>(lstm_kernel),
                      hipFuncAttributeMaxDynamicSharedMemorySize, SMEM_BYTES);

  size_t nz = 32768/8 + 4*PLANE/8;
  zero_kernel<<<(int)((nz + 255)/256), 256, 0, stream>>>(ws);
  lstm_kernel<<<NG*WPG, 256, SMEM_BYTES, stream>>>(x, s0, Wi0, Wh0, bi0, bh0,
                                                   Wi1, Wh1, bi1, bh1, Wfc, bfc,
                                                   out, ws);
}

// Round 9
// 20800.508 us; speedup vs baseline: 1.5304x; 1.5304x over previous
//
#include <hip/hip_runtime.h>
#include <cstdint>
#include <cstddef>

// ---------------- types ----------------
typedef __bf16 bf16;
typedef _Float16 f16;
typedef __bf16 bf16x8 __attribute__((ext_vector_type(8)));
typedef _Float16 f16x8 __attribute__((ext_vector_type(8)));
typedef float  f32x4  __attribute__((ext_vector_type(4)));
typedef unsigned int uint2v __attribute__((ext_vector_type(2)));
typedef unsigned int uint4v __attribute__((ext_vector_type(4)));
typedef unsigned long long u64;

// ---------------- problem sizes ----------------
constexpr int B_=256, T_=512, H_=512, X_=128, S_=64, IN0=192;
constexpr int NG=2;              // batch groups
constexpr int MG=128;            // rows per group
constexpr int WPG=128;           // workgroups per group (slices)
constexpr int KB_X=4, KB_H=16, KB_S=2;
constexpr float LOSCL = 4096.0f, INV_LOSCL = 1.0f/4096.0f;

// ---------------- ws layout ----------------
constexpr size_t OFF_FLG=0;                           // 2*128*64 = 16384 B
constexpr size_t OFF_BC =16384;                       // 2*64 B (pad to 32768)
constexpr size_t OFF_SC =32768;                       // [2][NG][64][128] f32 = 131072 B
constexpr size_t OFF_HP =OFF_SC+2ull*NG*64*128*4;     // 3 planes: H0H,H1H,H1L (f16)
constexpr size_t PLANE  =2ull*B_*H_*2;                // 524288 B each (double buffered)
constexpr size_t WS_NEED=OFF_HP+3*PLANE;              // ~1.8 MB

// ---------------- LDS ----------------
constexpr int NWX=KB_X*512;
constexpr int NWH=KB_H*512;
constexpr int NWS=KB_S*512;
constexpr int SMEM_BYTES = (2*NWX + 8*NWH + 2*NWS)*2
                         + 512*4 + 128*17*4 + 512*2*2 + 32*4;
static_assert(SMEM_BYTES == 156288, "lds size");
static_assert(SMEM_BYTES <= 160*1024, "lds limit");

// ---------------- coherent (agent-scope, L2-bypass) access ----------------
// 16B sc1 load: write-through/fabric-read semantics, barrier-separated data.
__device__ __forceinline__ uint4v ald16(const void* p) {
  uint4v r;
  asm volatile("global_load_dwordx4 %0, %1, off sc1"
               : "=&v"(r) : "v"(p) : "memory");
  return r;
}
__device__ __forceinline__ bf16x8 MKB(uint4v q) {
  union { uint4v q; bf16x8 v; } u; u.q = q;
  return u.v;
}
__device__ __forceinline__ f16x8 MKF(uint4v q) {
  union { uint4v q; f16x8 v; } u; u.q = q;
  return u.v;
}
__device__ __forceinline__ void astore8(void* p, uint2v v) {
  union { uint2v v; u64 q; } u; u.v = v;
  __hip_atomic_store((u64*)p, u.q, __ATOMIC_RELAXED, __HIP_MEMORY_SCOPE_AGENT);
}
__device__ __forceinline__ void astoref(float* p, float v) {
  __hip_atomic_store((unsigned*)p, __float_as_uint(v), __ATOMIC_RELAXED, __HIP_MEMORY_SCOPE_AGENT);
}
__device__ __forceinline__ float aloadf(const float* p) {
  return __uint_as_float(__hip_atomic_load((unsigned*)p, __ATOMIC_RELAXED, __HIP_MEMORY_SCOPE_AGENT));
}

// ---------------- helpers ----------------
__device__ __forceinline__ f32x4 mfmaB(bf16x8 a, bf16x8 b, f32x4 c) {
  return __builtin_amdgcn_mfma_f32_16x16x32_bf16(a, b, c, 0, 0, 0);
}
__device__ __forceinline__ f32x4 mfmaF(f16x8 a, f16x8 b, f32x4 c) {
  return __builtin_amdgcn_mfma_f32_16x16x32_f16(a, b, c, 0, 0, 0);
}
__device__ __forceinline__ f32x4 mfma3(bf16x8 ah, bf16x8 al, bf16x8 wh, bf16x8 wl, f32x4 c) {
  c = mfmaB(ah, wh, c);
  c = mfmaB(al, wh, c);
  c = mfmaB(ah, wl, c);
  return c;
}
__device__ __forceinline__ void split8p(const float* v, bf16x8& ah, bf16x8& al) {
  #pragma unroll
  for (int i=0;i<8;++i){ float f=v[i]; bf16 h=(bf16)f; ah[i]=h; al[i]=(bf16)(f-(float)h); }
}
__device__ __forceinline__ void split8v(f32x4 v0, f32x4 v1, bf16x8& ah, bf16x8& al) {
  #pragma unroll
  for (int i=0;i<4;++i){ float f=v0[i]; bf16 h=(bf16)f; ah[i]=h; al[i]=(bf16)(f-(float)h); }
  #pragma unroll
  for (int i=0;i<4;++i){ float f=v1[i]; bf16 h=(bf16)f; ah[4+i]=h; al[4+i]=(bf16)(f-(float)h); }
}
__device__ __forceinline__ float sigm(float v) { return 1.0f / (1.0f + __expf(-v)); }
__device__ __forceinline__ float tanhr(float v) {
  v = fminf(15.0f, fmaxf(-15.0f, v));
  float e = __expf(2.0f * v);
  return (e - 1.0f) / (e + 1.0f);
}

// Fence-free group barrier (R5/R7 proven; NO cache maintenance)
__device__ __forceinline__ void group_barrier(int* flg, int* bc, int ns, int& phase) {
  ++phase;
  const int p = phase;
  asm volatile("s_waitcnt vmcnt(0)" ::: "memory");
  __syncthreads();
  if (threadIdx.x == 0)
    __hip_atomic_store(flg + ns*16, p, __ATOMIC_RELAXED, __HIP_MEMORY_SCOPE_AGENT);
  if (ns == 0) {
    if (threadIdx.x < WPG) {
      while (__hip_atomic_load(flg + (int)threadIdx.x*16, __ATOMIC_RELAXED,
                               __HIP_MEMORY_SCOPE_AGENT) < p)
        __builtin_amdgcn_s_sleep(1);
    }
    __syncthreads();
    if (threadIdx.x == 0)
      __hip_atomic_store(bc, p, __ATOMIC_RELAXED, __HIP_MEMORY_SCOPE_AGENT);
  }
  if (threadIdx.x == 0) {
    while (__hip_atomic_load(bc, __ATOMIC_RELAXED, __HIP_MEMORY_SCOPE_AGENT) < p)
      __builtin_amdgcn_s_sleep(1);
  }
  __syncthreads();
}

// bf16 hi/lo pair pack (x and s chains)
__device__ void pack_slice(bf16* dH, bf16* dL, const float* src, int stride,
                           int koff, int nkb, int ns) {
  for (int p = (int)threadIdx.x; p < nkb*64; p += 256) {
    int ln = p & 63, kb = p >> 6;
    int c = ln & 15, k = kb*32 + ((ln>>4)<<3);
    int gcol = ((c>>2)<<9) + ns*4 + (c&3);
    const float* sp = src + (size_t)gcol*stride + koff + k;
    f32x4 v0 = *(const f32x4*)sp, v1 = *(const f32x4*)(sp+4);
    bf16x8 hv, lv;
    split8v(v0, v1, hv, lv);
    *(bf16x8*)(dH + p*8) = hv;
    *(bf16x8*)(dL + p*8) = lv;
  }
}
// f16 hi + 4096-scaled f16 lo pack (h chains; lo-scale dodges subnormal flush)
__device__ void pack_slice_f16(f16* dH, f16* dL, const float* src, int stride,
                               int koff, int nkb, int ns) {
  for (int p = (int)threadIdx.x; p < nkb*64; p += 256) {
    int ln = p & 63, kb = p >> 6;
    int c = ln & 15, k = kb*32 + ((ln>>4)<<3);
    int gcol = ((c>>2)<<9) + ns*4 + (c&3);
    const float* sp = src + (size_t)gcol*stride + koff + k;
    f16x8 hv; f16x8 lv;
    #pragma unroll
    for (int i=0;i<8;++i) {
      float f = sp[i];
      f16 h = (f16)f;
      hv[i] = h;
      lv[i] = (f16)((f - (float)h) * LOSCL);
    }
    *(f16x8*)(dH + p*8) = hv;
    *(f16x8*)(dL + p*8) = lv;
  }
}

// ---------------- zero kernel ----------------
__global__ void zero_kernel(char* __restrict__ ws) {
  size_t i = (size_t)blockIdx.x*256 + threadIdx.x;
  size_t nsync = 32768/8;
  if (i < nsync) {
    __hip_atomic_store((u64*)(ws+OFF_FLG) + i, 0ull,
                       __ATOMIC_RELAXED, __HIP_MEMORY_SCOPE_AGENT);
    return;
  }
  i -= nsync;
  if (i < 3*PLANE/8)
    __hip_atomic_store((u64*)(ws+OFF_HP) + i, 0ull,
                       __ATOMIC_RELAXED, __HIP_MEMORY_SCOPE_AGENT);
}

// ---------------- persistent LSTM kernel ----------------
#define FRB(base, kb) (*(const bf16x8*)((base) + (((kb)*64 + lane)*8)))
#define FRF(base, kb) (*(const f16x8*)((base) + (((kb)*64 + lane)*8)))

// f16 half-chain: 16 x 16B sc1 loads (2 mt x 8 kb, single plane), then MFMAs.
// hi -> acc, scaled-lo -> accL (caller folds accL * 1/4096).
template<bool DUAL>
__device__ __forceinline__ void chain8f(const f16* pA,
    const f16* sWH, const f16* sWL, const f16* sW2H, const f16* sW2L,
    int lane, const int* rowA, int kq, int kb0,
    f32x4* acc, f32x4* accL, f32x4* accB, f32x4* accBL)
{
  uint4v q[2][8];
  #pragma unroll
  for (int mt=0;mt<2;++mt) {
    const f16* bA = pA + (size_t)rowA[mt]*H_ + kb0*32 + kq;
    #pragma unroll
    for (int k=0;k<8;++k) q[mt][k] = ald16(bA + k*32);
  }
  asm volatile("s_waitcnt vmcnt(0)" ::: "memory");
  __builtin_amdgcn_sched_barrier(0);
  #pragma unroll
  for (int k=0;k<8;++k) {
    const int kb = kb0 + k;
    f16x8 wh = FRF(sWH,kb), wl = FRF(sWL,kb);
    #pragma unroll
    for (int mt=0;mt<2;++mt) {
      f16x8 a = MKF(q[mt][k]);
      acc[mt]  = mfmaF(a, wh, acc[mt]);
      accL[mt] = mfmaF(a, wl, accL[mt]);
      if (DUAL) {
        f16x8 w2h = FRF(sW2H,kb), w2l = FRF(sW2L,kb);
        accB[mt]  = mfmaF(a, w2h, accB[mt]);
        accBL[mt] = mfmaF(a, w2l, accBL[mt]);
      }
    }
  }
}

// fc half-row dot: f16 hi + f16 lo planes (exact-ish), fp32 dot with LDS weights
__device__ __forceinline__ float fc_half(const f16* hH, const f16* hL,
                                         const float* wp)
{
  float a = 0.f;
  #pragma unroll
  for (int half = 0; half < 2; ++half) {
    uint4v qh[16], ql[16];
    #pragma unroll
    for (int c2 = 0; c2 < 16; ++c2) {
      qh[c2] = ald16(hH + half*128 + c2*8);
      ql[c2] = ald16(hL + half*128 + c2*8);
    }
    asm volatile("s_waitcnt vmcnt(0)" ::: "memory");
    __builtin_amdgcn_sched_barrier(0);
    #pragma unroll
    for (int c2 = 0; c2 < 16; ++c2) {
      f16x8 hv = MKF(qh[c2]), lv = MKF(ql[c2]);
      const float* w2 = wp + half*128 + c2*8;
      f32x4 w0 = *(const f32x4*)w2, w1 = *(const f32x4*)(w2+4);
      a += ((float)hv[0]+(float)lv[0])*w0[0] + ((float)hv[1]+(float)lv[1])*w0[1]
         + ((float)hv[2]+(float)lv[2])*w0[2] + ((float)hv[3]+(float)lv[3])*w0[3]
         + ((float)hv[4]+(float)lv[4])*w1[0] + ((float)hv[5]+(float)lv[5])*w1[1]
         + ((float)hv[6]+(float)lv[6])*w1[2] + ((float)hv[7]+(float)lv[7])*w1[3];
    }
  }
  return a;
}

__global__ void __launch_bounds__(256, 1)
lstm_kernel(const float* __restrict__ x, const float* __restrict__ s0,
            const float* __restrict__ Wi0, const float* __restrict__ Wh0g,
            const float* __restrict__ bi0, const float* __restrict__ bh0,
            const float* __restrict__ Wi1g, const float* __restrict__ Wh1g,
            const float* __restrict__ bi1, const float* __restrict__ bh1,
            const float* __restrict__ Wfc, const float* __restrict__ bfc,
            float* __restrict__ out, char* __restrict__ ws)
{
  const int bid = blockIdx.x;
  const int g = bid & 1, ns = bid >> 1;
  const int tid = threadIdx.x;
  const int w = tid >> 6, lane = tid & 63, l15 = lane & 15;
  const int kq = (lane >> 4) << 3;
  const int mB = g * MG;
  int rowA[2];
  rowA[0] = mB + (w*2)*16 + l15;
  rowA[1] = rowA[0] + 16;

  int* flg = (int*)(ws + OFF_FLG) + g*128*16;
  int* bc  = (int*)(ws + OFF_BC) + g*16;
  float* SCbase = (float*)(ws + OFF_SC);
  f16* H0H_ = (f16*)(ws + OFF_HP);
  f16* H1H_ = (f16*)(ws + OFF_HP + PLANE);
  f16* H1L_ = (f16*)(ws + OFF_HP + 2*PLANE);

  extern __shared__ char smem[];
  bf16* sWxH  = (bf16*)smem;
  bf16* sWxL  = sWxH + NWX;
  f16* sWh0H = (f16*)(sWxL + NWX);
  f16* sWh0L = sWh0H + NWH;
  f16* sWcbH = sWh0L + NWH;
  f16* sWcbL = sWcbH + NWH;
  f16* sWi1H = sWcbL + NWH;
  f16* sWi1L = sWi1H + NWH;
  f16* sWh1H = sWi1L + NWH;
  f16* sWh1L = sWh1H + NWH;
  bf16* sWsH  = (bf16*)(sWh1L + NWH);
  bf16* sWsL  = sWsH + NWS;
  float* sWfc = (float*)(sWsL + NWS);
  float* sG   = sWfc + 512;
  f16*  sHh  = (f16*)(sG + 128*17);   // [128][4]
  f16*  sHl  = sHh + 512;             // [128][4] (h1 lo only)
  float* sB0  = (float*)(sHl + 512);
  float* sB1  = sB0 + 16;

  // ---- in-kernel weight packing ----
  pack_slice(sWxH,  sWxL,  Wi0,  IN0, 0,  KB_X, ns);        // bf16 pairs
  pack_slice_f16(sWh0H, sWh0L, Wh0g, H_,  0,  KB_H, ns);    // f16 + scaled lo
  pack_slice_f16(sWi1H, sWi1L, Wi1g, H_,  0,  KB_H, ns);
  pack_slice_f16(sWh1H, sWh1L, Wh1g, H_,  0,  KB_H, ns);
  pack_slice(sWsH,  sWsL,  Wi0,  IN0, X_, KB_S, ns);        // bf16 pairs
  for (int p = tid; p < KB_H*64; p += 256) {                // Wcomb (f16 + scaled lo)
    int ln = p & 63, kb = p >> 6;
    int c = ln & 15, k = kb*32 + ((ln>>4)<<3);
    int gcol = ((c>>2)<<9) + ns*4 + (c&3);
    const float* wis = Wi0 + (size_t)gcol*IN0 + X_;
    float a[8] = {0,0,0,0,0,0,0,0};
    for (int o = 0; o < S_; ++o) {
      float wv = wis[o];
      const float* fr = Wfc + (size_t)o*H_ + k;
      f32x4 f0 = *(const f32x4*)fr, f1 = *(const f32x4*)(fr+4);
      a[0]+=wv*f0[0]; a[1]+=wv*f0[1]; a[2]+=wv*f0[2]; a[3]+=wv*f0[3];
      a[4]+=wv*f1[0]; a[5]+=wv*f1[1]; a[6]+=wv*f1[2]; a[7]+=wv*f1[3];
    }
    f16x8 hv, lv;
    #pragma unroll
    for (int i=0;i<8;++i) {
      f16 h = (f16)a[i];
      hv[i] = h;
      lv[i] = (f16)((a[i] - (float)h) * LOSCL);
    }
    *(f16x8*)(sWcbH + p*8) = hv;
    *(f16x8*)(sWcbL + p*8) = lv;
  }
  for (int j = tid; j < H_; j += 256) sWfc[j] = Wfc[(size_t)(ns>>1)*H_ + j];
  if (tid < 16) {
    int gcol = ((tid>>2)<<9) + ns*4 + (tid&3);
    sB0[tid] = bi0[gcol] + bh0[gcol];
    sB1[tid] = bi1[gcol] + bh1[gcol];
  }

  float bfcW;
  {
    int gcol = ((l15>>2)<<9) + ns*4 + (l15&3);
    const float* wr = Wi0 + (size_t)gcol*IN0 + X_;
    float bw = 0.f;
    for (int o = 0; o < S_; ++o) bw += bfc[o]*wr[o];
    bfcW = bw;
  }
  const float bfc_ns = bfc[ns>>1];

  float s_reg[2][16];
  #pragma unroll
  for (int mt=0;mt<2;++mt)
    #pragma unroll
    for (int kb=0;kb<KB_S;++kb)
      #pragma unroll
      for (int i=0;i<8;++i)
        s_reg[mt][kb*8+i] = s0[(size_t)rowA[mt]*S_ + kb*32 + kq + i];

  __syncthreads();

  f32x4 Gs[2];
  #pragma unroll
  for (int mt=0;mt<2;++mt) {
    bf16x8 sh0,sl0,sh1,sl1;
    split8p(&s_reg[mt][0], sh0, sl0);
    split8p(&s_reg[mt][8], sh1, sl1);
    f32x4 a = (f32x4){0.f,0.f,0.f,0.f};
    a = mfma3(sh0, sl0, FRB(sWsH,0), FRB(sWsL,0), a);
    a = mfma3(sh1, sl1, FRB(sWsH,1), FRB(sWsL,1), a);
    Gs[mt] = a;
  }

  float c0s[2] = {0.f,0.f}, c1s[2] = {0.f,0.f};
  const int crow = tid >> 1;
  const int dbase = (tid & 1) << 1;
  const int frow = tid >> 1, fhalf = tid & 1;
  int phase = 0;

  for (int t = 0; t < T_; ++t) {
    const int rd = t & 1, wr = rd ^ 1;
    const size_t rdo = (size_t)rd*B_*H_, wro = (size_t)wr*B_*H_;
    float* SCp = SCbase + ((size_t)rd*NG + g)*(64*128);

    // ---- fc (even slices): out(t-1)[:, ns>>1] ----
    if (t > 0 && (ns & 1) == 0) {
      const f16* hH = H1H_ + rdo + (size_t)(mB+frow)*H_ + fhalf*256;
      const f16* hL = H1L_ + rdo + (size_t)(mB+frow)*H_ + fhalf*256;
      float a = fc_half(hH, hL, sWfc + fhalf*256);
      a += __shfl_xor(a, 1);
      if (fhalf == 0) {
        float o = a + bfc_ns;
        out[((size_t)(mB+frow)*T_ + (t-1))*S_ + (ns>>1)] = o;
        astoref(&SCp[(ns>>1)*128 + frow], o);
      }
    }

    // ---- phase-1 MFMA ----
    f32x4 acc0[2], acc0L[2], acc1[2], acc1L[2];
    {
      float addb = (t > 0) ? bfcW : 0.f;
      #pragma unroll
      for (int mt=0;mt<2;++mt) {
        #pragma unroll
        for (int r=0;r<4;++r) acc0[mt][r] = Gs[mt][r] + addb;
        acc0L[mt] = (f32x4){0.f,0.f,0.f,0.f};
        acc1[mt]  = (f32x4){0.f,0.f,0.f,0.f};
        acc1L[mt] = (f32x4){0.f,0.f,0.f,0.f};
      }
    }
    #pragma unroll
    for (int kb=0; kb<KB_X; ++kb) {          // x chain (cached loads, bf16 pairs)
      bf16x8 wh = FRB(sWxH,kb), wl = FRB(sWxL,kb);
      #pragma unroll
      for (int mt=0;mt<2;++mt) {
        const float* xp = x + ((size_t)rowA[mt]*T_ + t)*X_ + kb*32 + kq;
        bf16x8 ah, al2;
        split8v(*(const f32x4*)xp, *(const f32x4*)(xp+4), ah, al2);
        acc0[mt] = mfma3(ah, al2, wh, wl, acc0[mt]);
      }
    }
    // h1(t-1): shared A feeds Wcb (acc0) + Wh1 (acc1)
    chain8f<true>(H1H_+rdo, sWcbH, sWcbL, sWh1H, sWh1L, lane, rowA, kq, 0, acc0, acc0L, acc1, acc1L);
    chain8f<true>(H1H_+rdo, sWcbH, sWcbL, sWh1H, sWh1L, lane, rowA, kq, 8, acc0, acc0L, acc1, acc1L);
    // h0(t-1): acc0
    chain8f<false>(H0H_+rdo, sWh0H, sWh0L, sWh0H, sWh0L, lane, rowA, kq, 0, acc0, acc0L, acc1, acc1L);
    chain8f<false>(H0H_+rdo, sWh0H, sWh0L, sWh0H, sWh0L, lane, rowA, kq, 8, acc0, acc0L, acc1, acc1L);

    // fold scaled-lo + bounce C -> (row, gatecol)
    #pragma unroll
    for (int mt=0;mt<2;++mt)
      #pragma unroll
      for (int r=0;r<4;++r)
        sG[((w*2+mt)*16 + ((lane>>4)<<2) + r)*17 + l15] =
            acc0[mt][r] + acc0L[mt][r]*INV_LOSCL;
    __syncthreads();
    {   // cell 0 (h0 stored as single f16)
      const float* gr = sG + crow*17;
      #pragma unroll
      for (int j=0;j<2;++j) {
        int d = dbase + j;
        float gi = gr[d]    + sB0[d];
        float gf = gr[4+d]  + sB0[4+d];
        float gg = gr[8+d]  + sB0[8+d];
        float go = gr[12+d] + sB0[12+d];
        c0s[j] = sigm(gf)*c0s[j] + sigm(gi)*tanhr(gg);
        sHh[crow*4+d] = (f16)(sigm(go)*tanhr(c0s[j]));
      }
    }
    __syncthreads();
    if (tid < MG) {
      size_t off = wro + (size_t)(mB+tid)*H_ + ns*4;
      astore8(H0H_ + off, *(const uint2v*)(sHh + tid*4));
    }
    group_barrier(flg, bc, ns, phase);   // A: h0(t) + out columns visible

    // ---- s(t) = s(t-1) + out(t-1); fresh Gs ----
    if (t > 0) {
      const float* SCr = SCbase + ((size_t)rd*NG + g)*(64*128);
      #pragma unroll
      for (int mt=0;mt<2;++mt) {
        int rloc = (w*2+mt)*16 + l15;
        #pragma unroll
        for (int kb=0;kb<KB_S;++kb)
          #pragma unroll
          for (int i=0;i<8;++i)
            s_reg[mt][kb*8+i] += aloadf(&SCr[(kb*32+kq+i)*128 + rloc]);
      }
    }
    #pragma unroll
    for (int mt=0;mt<2;++mt) {
      bf16x8 sh0,sl0,sh1,sl1;
      split8p(&s_reg[mt][0], sh0, sl0);
      split8p(&s_reg[mt][8], sh1, sl1);
      f32x4 a = (f32x4){0.f,0.f,0.f,0.f};
      a = mfma3(sh0, sl0, FRB(sWsH,0), FRB(sWsL,0), a);
      a = mfma3(sh1, sl1, FRB(sWsH,1), FRB(sWsL,1), a);
      Gs[mt] = a;
    }

    // ---- layer 1: acc1 += h0(t).Wi1 ----
    chain8f<false>(H0H_+wro, sWi1H, sWi1L, sWi1H, sWi1L, lane, rowA, kq, 0, acc1, acc1L, acc0, acc0L);
    chain8f<false>(H0H_+wro, sWi1H, sWi1L, sWi1H, sWi1L, lane, rowA, kq, 8, acc1, acc1L, acc0, acc0L);

    #pragma unroll
    for (int mt=0;mt<2;++mt)
      #pragma unroll
      for (int r=0;r<4;++r)
        sG[((w*2+mt)*16 + ((lane>>4)<<2) + r)*17 + l15] =
            acc1[mt][r] + acc1L[mt][r]*INV_LOSCL;
    __syncthreads();
    {   // cell 1 (h1 stored as f16 + f16 lo)
      const float* gr = sG + crow*17;
      #pragma unroll
      for (int j=0;j<2;++j) {
        int d = dbase + j;
        float gi = gr[d]    + sB1[d];
        float gf = gr[4+d]  + sB1[4+d];
        float gg = gr[8+d]  + sB1[8+d];
        float go = gr[12+d] + sB1[12+d];
        c1s[j] = sigm(gf)*c1s[j] + sigm(gi)*tanhr(gg);
        float h = sigm(go)*tanhr(c1s[j]);
        f16 hh = (f16)h;
        sHh[crow*4+d] = hh;
        sHl[crow*4+d] = (f16)(h - (float)hh);
      }
    }
    __syncthreads();
    if (tid < MG) {
      size_t off = wro + (size_t)(mB+tid)*H_ + ns*4;
      astore8(H1H_ + off, *(const uint2v*)(sHh + tid*4));
      astore8(H1L_ + off, *(const uint2v*)(sHl + tid*4));
    }
    group_barrier(flg, bc, ns, phase);   // B: h1(t) visible
  }

  // ---- epilogue: out(T-1) ----
  if ((ns & 1) == 0) {
    const f16* hH = H1H_ + (size_t)(mB+frow)*H_ + fhalf*256;
    const f16* hL = H1L_ + (size_t)(mB+frow)*H_ + fhalf*256;
    float a = fc_half(hH, hL, sWfc + fhalf*256);
    a += __shfl_xor(a, 1);
    if (fhalf == 0)
      out[((size_t)(mB+frow)*T_ + (T_-1))*S_ + (ns>>1)] = a + bfc_ns;
  }
}

// ---------------- launcher ----------------
extern "C" void kernel_launch(void* const* d_in, const int* in_sizes, int n_in,
                              void* d_out, int out_size, void* d_ws, size_t ws_size,
                              hipStream_t stream)
{
  const float* x   = (const float*)d_in[0];
  const float* s0  = (const float*)d_in[1];
  const float* Wi0 = (const float*)d_in[2];
  const float* Wh0 = (const float*)d_in[3];
  const float* bi0 = (const float*)d_in[4];
  const float* bh0 = (const float*)d_in[5];
  const float* Wi1 = (const float*)d_in[6];
  const float* Wh1 = (const float*)d_in[7];
  const float* bi1 = (const float*)d_in[8];
  const float* bh1 = (const float*)d_in[9];
  const float* Wfc = (const float*)d_in[10];
  const float* bfc = (const float*)d_in[11];
  float* out = (float*)d_out;
  char* ws = (char*)d_ws;

  if (ws_size < WS_NEED) return;

  hipFuncSetAttribute(reinterpret_cast<const void*>(lstm_kernel),
                      hipFuncAttributeMaxDynamicSharedMemorySize, SMEM_BYTES);

  size_t nz = 32768/8 + 3*PLANE/8;
  zero_kernel<<<(int)((nz + 255)/256), 256, 0, stream>>>(ws);
  lstm_kernel<<<NG*WPG, 256, SMEM_BYTES, stream>>>(x, s0, Wi0, Wh0, bi0, bh0,
                                                   Wi1, Wh1, bi1, bh1, Wfc, bfc,
                                                   out, ws);
}

// Round 10
// 10157.953 us; speedup vs baseline: 3.1338x; 2.0477x over previous
//
#include <hip/hip_runtime.h>
#include <cstdint>
#include <cstddef>

// ---------------- types ----------------
typedef __bf16 bf16;
typedef _Float16 f16;
typedef __bf16 bf16x8 __attribute__((ext_vector_type(8)));
typedef _Float16 f16x8 __attribute__((ext_vector_type(8)));
typedef float  f32x4  __attribute__((ext_vector_type(4)));
typedef unsigned int uint2v __attribute__((ext_vector_type(2)));
typedef unsigned int uint4v __attribute__((ext_vector_type(4)));
typedef unsigned long long u64;

// ---------------- problem sizes ----------------
constexpr int B_=256, T_=512, H_=512, X_=128, S_=64, IN0=192;
constexpr int NG=2;              // batch groups
constexpr int MG=128;            // rows per group
constexpr int WPG=128;           // workgroups per group (slices)
constexpr int KB_X=4, KB_H=16, KB_S=2;
constexpr float LOSCL = 4096.0f, INV_LOSCL = 1.0f/4096.0f;

// ---------------- ws layout ----------------
constexpr size_t OFF_FLG=0;                           // 2*128*64 = 16384 B
constexpr size_t OFF_BC =16384;                       // 2*64 B (pad to 32768)
constexpr size_t OFF_SC =32768;                       // [2][NG][64][128] f32 = 131072 B
constexpr size_t OFF_HP =OFF_SC+2ull*NG*64*128*4;     // 2 planes: H0H, H1H (f16)
constexpr size_t PLANE  =2ull*B_*H_*2;                // 524288 B each (double buffered)
constexpr size_t WS_NEED=OFF_HP+2*PLANE;              // ~1.3 MB

// ---------------- LDS ----------------
constexpr int NWX=KB_X*512;
constexpr int NWH=KB_H*512;
constexpr int NWS=KB_S*512;
// x pair(8KB) + 4 h-chain pairs(128KB) + s pair(4KB) + wfc pair f16(2KB)
// + sG(8.5KB) + sHh(1KB) + biases
constexpr int SMEM_BYTES = (2*NWX + 8*NWH + 2*NWS)*2
                         + 2*512*2 + 128*17*4 + 512*2 + 32*4;
static_assert(SMEM_BYTES == 155264, "lds size");
static_assert(SMEM_BYTES <= 160*1024, "lds limit");

// ---------------- coherent (agent-scope, L2-bypass) access ----------------
__device__ __forceinline__ uint4v ald16(const void* p) {
  uint4v r;
  asm volatile("global_load_dwordx4 %0, %1, off sc1"
               : "=&v"(r) : "v"(p) : "memory");
  return r;
}
__device__ __forceinline__ f16x8 MKF(uint4v q) {
  union { uint4v q; f16x8 v; } u; u.q = q;
  return u.v;
}
__device__ __forceinline__ void astore8(void* p, uint2v v) {
  union { uint2v v; u64 q; } u; u.v = v;
  __hip_atomic_store((u64*)p, u.q, __ATOMIC_RELAXED, __HIP_MEMORY_SCOPE_AGENT);
}
__device__ __forceinline__ void astoref(float* p, float v) {
  __hip_atomic_store((unsigned*)p, __float_as_uint(v), __ATOMIC_RELAXED, __HIP_MEMORY_SCOPE_AGENT);
}
__device__ __forceinline__ float aloadf(const float* p) {
  return __uint_as_float(__hip_atomic_load((unsigned*)p, __ATOMIC_RELAXED, __HIP_MEMORY_SCOPE_AGENT));
}

// ---------------- helpers ----------------
__device__ __forceinline__ f32x4 mfmaB(bf16x8 a, bf16x8 b, f32x4 c) {
  return __builtin_amdgcn_mfma_f32_16x16x32_bf16(a, b, c, 0, 0, 0);
}
__device__ __forceinline__ f32x4 mfmaF(f16x8 a, f16x8 b, f32x4 c) {
  return __builtin_amdgcn_mfma_f32_16x16x32_f16(a, b, c, 0, 0, 0);
}
__device__ __forceinline__ f32x4 mfma3(bf16x8 ah, bf16x8 al, bf16x8 wh, bf16x8 wl, f32x4 c) {
  c = mfmaB(ah, wh, c);
  c = mfmaB(al, wh, c);
  c = mfmaB(ah, wl, c);
  return c;
}
__device__ __forceinline__ void split8p(const float* v, bf16x8& ah, bf16x8& al) {
  #pragma unroll
  for (int i=0;i<8;++i){ float f=v[i]; bf16 h=(bf16)f; ah[i]=h; al[i]=(bf16)(f-(float)h); }
}
__device__ __forceinline__ void split8v(f32x4 v0, f32x4 v1, bf16x8& ah, bf16x8& al) {
  #pragma unroll
  for (int i=0;i<4;++i){ float f=v0[i]; bf16 h=(bf16)f; ah[i]=h; al[i]=(bf16)(f-(float)h); }
  #pragma unroll
  for (int i=0;i<4;++i){ float f=v1[i]; bf16 h=(bf16)f; ah[4+i]=h; al[4+i]=(bf16)(f-(float)h); }
}
__device__ __forceinline__ float sigm(float v) { return 1.0f / (1.0f + __expf(-v)); }
__device__ __forceinline__ float tanhr(float v) {
  v = fminf(15.0f, fmaxf(-15.0f, v));
  float e = __expf(2.0f * v);
  return (e - 1.0f) / (e + 1.0f);
}

// Fence-free group barrier (R5/R7/R9 proven)
__device__ __forceinline__ void group_barrier(int* flg, int* bc, int ns, int& phase) {
  ++phase;
  const int p = phase;
  asm volatile("s_waitcnt vmcnt(0)" ::: "memory");
  __syncthreads();
  if (threadIdx.x == 0)
    __hip_atomic_store(flg + ns*16, p, __ATOMIC_RELAXED, __HIP_MEMORY_SCOPE_AGENT);
  if (ns == 0) {
    if (threadIdx.x < WPG) {
      while (__hip_atomic_load(flg + (int)threadIdx.x*16, __ATOMIC_RELAXED,
                               __HIP_MEMORY_SCOPE_AGENT) < p)
        __builtin_amdgcn_s_sleep(1);
    }
    __syncthreads();
    if (threadIdx.x == 0)
      __hip_atomic_store(bc, p, __ATOMIC_RELAXED, __HIP_MEMORY_SCOPE_AGENT);
  }
  if (threadIdx.x == 0) {
    while (__hip_atomic_load(bc, __ATOMIC_RELAXED, __HIP_MEMORY_SCOPE_AGENT) < p)
      __builtin_amdgcn_s_sleep(1);
  }
  __syncthreads();
}

// bf16 hi/lo pair pack (x and s chains)
__device__ void pack_slice(bf16* dH, bf16* dL, const float* src, int stride,
                           int koff, int nkb, int ns) {
  for (int p = (int)threadIdx.x; p < nkb*64; p += 256) {
    int ln = p & 63, kb = p >> 6;
    int c = ln & 15, k = kb*32 + ((ln>>4)<<3);
    int gcol = ((c>>2)<<9) + ns*4 + (c&3);
    const float* sp = src + (size_t)gcol*stride + koff + k;
    f32x4 v0 = *(const f32x4*)sp, v1 = *(const f32x4*)(sp+4);
    bf16x8 hv, lv;
    split8v(v0, v1, hv, lv);
    *(bf16x8*)(dH + p*8) = hv;
    *(bf16x8*)(dL + p*8) = lv;
  }
}
// f16 hi + 4096-scaled f16 lo pack (h chains)
__device__ void pack_slice_f16(f16* dH, f16* dL, const float* src, int stride,
                               int koff, int nkb, int ns) {
  for (int p = (int)threadIdx.x; p < nkb*64; p += 256) {
    int ln = p & 63, kb = p >> 6;
    int c = ln & 15, k = kb*32 + ((ln>>4)<<3);
    int gcol = ((c>>2)<<9) + ns*4 + (c&3);
    const float* sp = src + (size_t)gcol*stride + koff + k;
    f16x8 hv; f16x8 lv;
    #pragma unroll
    for (int i=0;i<8;++i) {
      float f = sp[i];
      f16 h = (f16)f;
      hv[i] = h;
      lv[i] = (f16)((f - (float)h) * LOSCL);
    }
    *(f16x8*)(dH + p*8) = hv;
    *(f16x8*)(dL + p*8) = lv;
  }
}

// ---------------- zero kernel ----------------
__global__ void zero_kernel(char* __restrict__ ws) {
  size_t i = (size_t)blockIdx.x*256 + threadIdx.x;
  size_t nsync = 32768/8;
  if (i < nsync) {
    __hip_atomic_store((u64*)(ws+OFF_FLG) + i, 0ull,
                       __ATOMIC_RELAXED, __HIP_MEMORY_SCOPE_AGENT);
    return;
  }
  i -= nsync;
  if (i < 2*PLANE/8)
    __hip_atomic_store((u64*)(ws+OFF_HP) + i, 0ull,
                       __ATOMIC_RELAXED, __HIP_MEMORY_SCOPE_AGENT);
}

// ---------------- persistent LSTM kernel ----------------
#define FRB(base, kb) (*(const bf16x8*)((base) + (((kb)*64 + lane)*8)))
#define FRF(base, kb) (*(const f16x8*)((base) + (((kb)*64 + lane)*8)))
#define WFC(base, kb) (*(const f16x8*)((base) + (kb)*32 + kq))

__global__ void __launch_bounds__(256, 1)
lstm_kernel(const float* __restrict__ x, const float* __restrict__ s0,
            const float* __restrict__ Wi0, const float* __restrict__ Wh0g,
            const float* __restrict__ bi0, const float* __restrict__ bh0,
            const float* __restrict__ Wi1g, const float* __restrict__ Wh1g,
            const float* __restrict__ bi1, const float* __restrict__ bh1,
            const float* __restrict__ Wfc, const float* __restrict__ bfc,
            float* __restrict__ out, char* __restrict__ ws)
{
  const int bid = blockIdx.x;
  const int g = bid & 1, ns = bid >> 1;
  const int tid = threadIdx.x;
  const int w = tid >> 6, lane = tid & 63, l15 = lane & 15;
  const int kq = (lane >> 4) << 3;
  const int mB = g * MG;
  const bool evenNs = (ns & 1) == 0;
  const int cstar = ns >> 1;            // out column owned (even slices write)
  int rowA[2];
  rowA[0] = mB + (w*2)*16 + l15;
  rowA[1] = rowA[0] + 16;

  int* flg = (int*)(ws + OFF_FLG) + g*128*16;
  int* bc  = (int*)(ws + OFF_BC) + g*16;
  float* SCbase = (float*)(ws + OFF_SC);
  f16* H0H_ = (f16*)(ws + OFF_HP);
  f16* H1H_ = (f16*)(ws + OFF_HP + PLANE);

  extern __shared__ char smem[];
  bf16* sWxH  = (bf16*)smem;
  bf16* sWxL  = sWxH + NWX;
  f16* sWh0H = (f16*)(sWxL + NWX);
  f16* sWh0L = sWh0H + NWH;
  f16* sWcbH = sWh0L + NWH;
  f16* sWcbL = sWcbH + NWH;
  f16* sWi1H = sWcbL + NWH;
  f16* sWi1L = sWi1H + NWH;
  f16* sWh1H = sWi1L + NWH;
  f16* sWh1L = sWh1H + NWH;
  bf16* sWsH  = (bf16*)(sWh1L + NWH);
  bf16* sWsL  = sWsH + NWS;
  f16* sWfcH = (f16*)(sWsL + NWS);    // [512] f16 hi of W_fc row cstar
  f16* sWfcL = sWfcH + 512;           // [512] f16 scaled lo
  float* sG   = (float*)(sWfcL + 512);
  f16*  sHh  = (f16*)(sG + 128*17);   // [128][4]
  float* sB0  = (float*)(sHh + 512);
  float* sB1  = sB0 + 16;

  // ---- in-kernel weight packing ----
  pack_slice(sWxH,  sWxL,  Wi0,  IN0, 0,  KB_X, ns);
  pack_slice_f16(sWh0H, sWh0L, Wh0g, H_,  0,  KB_H, ns);
  pack_slice_f16(sWi1H, sWi1L, Wi1g, H_,  0,  KB_H, ns);
  pack_slice_f16(sWh1H, sWh1L, Wh1g, H_,  0,  KB_H, ns);
  pack_slice(sWsH,  sWsL,  Wi0,  IN0, X_, KB_S, ns);
  for (int p = tid; p < KB_H*64; p += 256) {                // Wcomb (f16 + scaled lo)
    int ln = p & 63, kb = p >> 6;
    int c = ln & 15, k = kb*32 + ((ln>>4)<<3);
    int gcol = ((c>>2)<<9) + ns*4 + (c&3);
    const float* wis = Wi0 + (size_t)gcol*IN0 + X_;
    float a[8] = {0,0,0,0,0,0,0,0};
    for (int o = 0; o < S_; ++o) {
      float wv = wis[o];
      const float* fr = Wfc + (size_t)o*H_ + k;
      f32x4 f0 = *(const f32x4*)fr, f1 = *(const f32x4*)(fr+4);
      a[0]+=wv*f0[0]; a[1]+=wv*f0[1]; a[2]+=wv*f0[2]; a[3]+=wv*f0[3];
      a[4]+=wv*f1[0]; a[5]+=wv*f1[1]; a[6]+=wv*f1[2]; a[7]+=wv*f1[3];
    }
    f16x8 hv, lv;
    #pragma unroll
    for (int i=0;i<8;++i) {
      f16 h = (f16)a[i];
      hv[i] = h;
      lv[i] = (f16)((a[i] - (float)h) * LOSCL);
    }
    *(f16x8*)(sWcbH + p*8) = hv;
    *(f16x8*)(sWcbL + p*8) = lv;
  }
  for (int j = tid; j < H_; j += 256) {
    float f = Wfc[(size_t)cstar*H_ + j];
    f16 h = (f16)f;
    sWfcH[j] = h;
    sWfcL[j] = (f16)((f - (float)h) * LOSCL);
  }
  if (tid < 16) {
    int gcol = ((tid>>2)<<9) + ns*4 + (tid&3);
    sB0[tid] = bi0[gcol] + bh0[gcol];
    sB1[tid] = bi1[gcol] + bh1[gcol];
  }

  float bfcW;
  {
    int gcol = ((l15>>2)<<9) + ns*4 + (l15&3);
    const float* wr = Wi0 + (size_t)gcol*IN0 + X_;
    float bw = 0.f;
    for (int o = 0; o < S_; ++o) bw += bfc[o]*wr[o];
    bfcW = bw;
  }
  const float bfc_ns = bfc[cstar];

  float s_reg[2][16];
  #pragma unroll
  for (int mt=0;mt<2;++mt)
    #pragma unroll
    for (int kb=0;kb<KB_S;++kb)
      #pragma unroll
      for (int i=0;i<8;++i)
        s_reg[mt][kb*8+i] = s0[(size_t)rowA[mt]*S_ + kb*32 + kq + i];

  __syncthreads();

  f32x4 Gs[2];
  #pragma unroll
  for (int mt=0;mt<2;++mt) {
    bf16x8 sh0,sl0,sh1,sl1;
    split8p(&s_reg[mt][0], sh0, sl0);
    split8p(&s_reg[mt][8], sh1, sl1);
    f32x4 a = (f32x4){0.f,0.f,0.f,0.f};
    a = mfma3(sh0, sl0, FRB(sWsH,0), FRB(sWsL,0), a);
    a = mfma3(sh1, sl1, FRB(sWsH,1), FRB(sWsL,1), a);
    Gs[mt] = a;
  }

  // carried h0 fragments (h0(t-1) in fragment layout); zero at t=0
  uint4v c0q[2][16];
  #pragma unroll
  for (int mt=0;mt<2;++mt)
    #pragma unroll
    for (int kb=0;kb<16;++kb) c0q[mt][kb] = (uint4v){0,0,0,0};

  float c0s[2] = {0.f,0.f}, c1s[2] = {0.f,0.f};
  const int crow = tid >> 1;
  const int dbase = (tid & 1) << 1;
  int phase = 0;

  for (int t = 0; t < T_; ++t) {
    const int rd = t & 1, wr = rd ^ 1;
    const size_t rdo = (size_t)rd*B_*H_, wro = (size_t)wr*B_*H_;
    float* SCp = SCbase + ((size_t)rd*NG + g)*(64*128);

    // ---- phase-1: acc0 = Gs+bfcW + x.Wx + h1.Wcb + h0carry.Wh0 ; acc1 = h1.Wh1 ;
    //               accF = h1.Wfc (fc via MFMA, reuses h1 fragments)
    f32x4 acc0[2], acc0L[2], acc1[2], acc1L[2], accF[2], accFL[2];
    {
      float addb = (t > 0) ? bfcW : 0.f;
      #pragma unroll
      for (int mt=0;mt<2;++mt) {
        #pragma unroll
        for (int r=0;r<4;++r) acc0[mt][r] = Gs[mt][r] + addb;
        acc0L[mt] = (f32x4){0.f,0.f,0.f,0.f};
        acc1[mt]  = (f32x4){0.f,0.f,0.f,0.f};
        acc1L[mt] = (f32x4){0.f,0.f,0.f,0.f};
        accF[mt]  = (f32x4){0.f,0.f,0.f,0.f};
        accFL[mt] = (f32x4){0.f,0.f,0.f,0.f};
      }
    }
    #pragma unroll
    for (int kb=0; kb<KB_X; ++kb) {          // x chain (cached loads, bf16 pairs)
      bf16x8 wh = FRB(sWxH,kb), wl = FRB(sWxL,kb);
      #pragma unroll
      for (int mt=0;mt<2;++mt) {
        const float* xp = x + ((size_t)rowA[mt]*T_ + t)*X_ + kb*32 + kq;
        bf16x8 ah, al2;
        split8v(*(const f32x4*)xp, *(const f32x4*)(xp+4), ah, al2);
        acc0[mt] = mfma3(ah, al2, wh, wl, acc0[mt]);
      }
    }
    // h1(t-1) chain: 2 half-batches; fragments feed Wcb + Wh1 + Wfc
    #pragma unroll
    for (int hb=0; hb<2; ++hb) {
      const int kb0 = hb*8;
      uint4v q[2][8];
      #pragma unroll
      for (int mt=0;mt<2;++mt) {
        const f16* bA = H1H_ + rdo + (size_t)rowA[mt]*H_ + kb0*32 + kq;
        #pragma unroll
        for (int k=0;k<8;++k) q[mt][k] = ald16(bA + k*32);
      }
      asm volatile("s_waitcnt vmcnt(0)" ::: "memory");
      __builtin_amdgcn_sched_barrier(0);
      #pragma unroll
      for (int k=0;k<8;++k) {
        const int kb = kb0 + k;
        f16x8 cbh = FRF(sWcbH,kb), cbl = FRF(sWcbL,kb);
        f16x8 whh = FRF(sWh1H,kb), whl = FRF(sWh1L,kb);
        f16x8 fH  = WFC(sWfcH,kb),  fL = WFC(sWfcL,kb);
        #pragma unroll
        for (int mt=0;mt<2;++mt) {
          f16x8 a = MKF(q[mt][k]);
          acc0[mt]  = mfmaF(a, cbh, acc0[mt]);
          acc0L[mt] = mfmaF(a, cbl, acc0L[mt]);
          acc1[mt]  = mfmaF(a, whh, acc1[mt]);
          acc1L[mt] = mfmaF(a, whl, acc1L[mt]);
          accF[mt]  = mfmaF(a, fH,  accF[mt]);
          accFL[mt] = mfmaF(a, fL,  accFL[mt]);
        }
      }
    }
    // h0(t-1) from REGISTER CARRY (no loads)
    #pragma unroll
    for (int kb=0; kb<KB_H; ++kb) {
      f16x8 wh = FRF(sWh0H,kb), wl = FRF(sWh0L,kb);
      #pragma unroll
      for (int mt=0;mt<2;++mt) {
        f16x8 a = MKF(c0q[mt][kb]);
        acc0[mt]  = mfmaF(a, wh, acc0[mt]);
        acc0L[mt] = mfmaF(a, wl, acc0L[mt]);
      }
    }
    // fc write: out(t-1)[:, cstar] from accF (C layout: row=(lane>>4)*4+r, all cols equal)
    if (t > 0 && evenNs && l15 == 0) {
      #pragma unroll
      for (int mt=0;mt<2;++mt)
        #pragma unroll
        for (int r=0;r<4;++r) {
          int rloc = (w*2+mt)*16 + ((lane>>4)<<2) + r;
          float o = accF[mt][r] + accFL[mt][r]*INV_LOSCL + bfc_ns;
          out[((size_t)(mB+rloc)*T_ + (t-1))*S_ + cstar] = o;
          astoref(&SCp[cstar*128 + rloc], o);
        }
    }

    // bounce C -> (row, gatecol)
    #pragma unroll
    for (int mt=0;mt<2;++mt)
      #pragma unroll
      for (int r=0;r<4;++r)
        sG[((w*2+mt)*16 + ((lane>>4)<<2) + r)*17 + l15] =
            acc0[mt][r] + acc0L[mt][r]*INV_LOSCL;
    __syncthreads();
    {   // cell 0 (h0 stored as single f16)
      const float* gr = sG + crow*17;
      #pragma unroll
      for (int j=0;j<2;++j) {
        int d = dbase + j;
        float gi = gr[d]    + sB0[d];
        float gf = gr[4+d]  + sB0[4+d];
        float gg = gr[8+d]  + sB0[8+d];
        float go = gr[12+d] + sB0[12+d];
        c0s[j] = sigm(gf)*c0s[j] + sigm(gi)*tanhr(gg);
        sHh[crow*4+d] = (f16)(sigm(go)*tanhr(c0s[j]));
      }
    }
    __syncthreads();
    if (tid < MG) {
      size_t off = wro + (size_t)(mB+tid)*H_ + ns*4;
      astore8(H0H_ + off, *(const uint2v*)(sHh + tid*4));
    }
    group_barrier(flg, bc, ns, phase);   // A: h0(t) + out columns visible

    // ---- s(t) = s(t-1) + out(t-1); fresh Gs ----
    if (t > 0) {
      const float* SCr = SCbase + ((size_t)rd*NG + g)*(64*128);
      #pragma unroll
      for (int mt=0;mt<2;++mt) {
        int rloc = (w*2+mt)*16 + l15;
        #pragma unroll
        for (int kb=0;kb<KB_S;++kb)
          #pragma unroll
          for (int i=0;i<8;++i)
            s_reg[mt][kb*8+i] += aloadf(&SCr[(kb*32+kq+i)*128 + rloc]);
      }
    }
    #pragma unroll
    for (int mt=0;mt<2;++mt) {
      bf16x8 sh0,sl0,sh1,sl1;
      split8p(&s_reg[mt][0], sh0, sl0);
      split8p(&s_reg[mt][8], sh1, sl1);
      f32x4 a = (f32x4){0.f,0.f,0.f,0.f};
      a = mfma3(sh0, sl0, FRB(sWsH,0), FRB(sWsL,0), a);
      a = mfma3(sh1, sl1, FRB(sWsH,1), FRB(sWsL,1), a);
      Gs[mt] = a;
    }

    // ---- layer 1: load h0(t) fragments INTO CARRY, acc1 += h0(t).Wi1 ----
    #pragma unroll
    for (int hb=0; hb<2; ++hb) {
      const int kb0 = hb*8;
      #pragma unroll
      for (int mt=0;mt<2;++mt) {
        const f16* bA = H0H_ + wro + (size_t)rowA[mt]*H_ + kb0*32 + kq;
        #pragma unroll
        for (int k=0;k<8;++k) c0q[mt][kb0+k] = ald16(bA + k*32);
      }
      asm volatile("s_waitcnt vmcnt(0)" ::: "memory");
      __builtin_amdgcn_sched_barrier(0);
      #pragma unroll
      for (int k=0;k<8;++k) {
        const int kb = kb0 + k;
        f16x8 wh = FRF(sWi1H,kb), wl = FRF(sWi1L,kb);
        #pragma unroll
        for (int mt=0;mt<2;++mt) {
          f16x8 a = MKF(c0q[mt][kb]);
          acc1[mt]  = mfmaF(a, wh, acc1[mt]);
          acc1L[mt] = mfmaF(a, wl, acc1L[mt]);
        }
      }
    }

    #pragma unroll
    for (int mt=0;mt<2;++mt)
      #pragma unroll
      for (int r=0;r<4;++r)
        sG[((w*2+mt)*16 + ((lane>>4)<<2) + r)*17 + l15] =
            acc1[mt][r] + acc1L[mt][r]*INV_LOSCL;
    __syncthreads();
    {   // cell 1 (h1 stored as single f16)
      const float* gr = sG + crow*17;
      #pragma unroll
      for (int j=0;j<2;++j) {
        int d = dbase + j;
        float gi = gr[d]    + sB1[d];
        float gf = gr[4+d]  + sB1[4+d];
        float gg = gr[8+d]  + sB1[8+d];
        float go = gr[12+d] + sB1[12+d];
        c1s[j] = sigm(gf)*c1s[j] + sigm(gi)*tanhr(gg);
        sHh[crow*4+d] = (f16)(sigm(go)*tanhr(c1s[j]));
      }
    }
    __syncthreads();
    if (tid < MG) {
      size_t off = wro + (size_t)(mB+tid)*H_ + ns*4;
      astore8(H1H_ + off, *(const uint2v*)(sHh + tid*4));
    }
    group_barrier(flg, bc, ns, phase);   // B: h1(t) visible
  }

  // ---- epilogue: out(T-1) via fc-MFMA on h1(T-1) (buffer 0) ----
  if (evenNs) {
    f32x4 accF[2], accFL[2];
    #pragma unroll
    for (int mt=0;mt<2;++mt) {
      accF[mt]  = (f32x4){0.f,0.f,0.f,0.f};
      accFL[mt] = (f32x4){0.f,0.f,0.f,0.f};
    }
    #pragma unroll
    for (int hb=0; hb<2; ++hb) {
      const int kb0 = hb*8;
      uint4v q[2][8];
      #pragma unroll
      for (int mt=0;mt<2;++mt) {
        const f16* bA = H1H_ + (size_t)rowA[mt]*H_ + kb0*32 + kq;
        #pragma unroll
        for (int k=0;k<8;++k) q[mt][k] = ald16(bA + k*32);
      }
      asm volatile("s_waitcnt vmcnt(0)" ::: "memory");
      __builtin_amdgcn_sched_barrier(0);
      #pragma unroll
      for (int k=0;k<8;++k) {
        const int kb = kb0 + k;
        f16x8 fH = WFC(sWfcH,kb), fL = WFC(sWfcL,kb);
        #pragma unroll
        for (int mt=0;mt<2;++mt) {
          f16x8 a = MKF(q[mt][k]);
          accF[mt]  = mfmaF(a, fH, accF[mt]);
          accFL[mt] = mfmaF(a, fL, accFL[mt]);
        }
      }
    }
    if (l15 == 0) {
      #pragma unroll
      for (int mt=0;mt<2;++mt)
        #pragma unroll
        for (int r=0;r<4;++r) {
          int rloc = (w*2+mt)*16 + ((lane>>4)<<2) + r;
          float o = accF[mt][r] + accFL[mt][r]*INV_LOSCL + bfc_ns;
          out[((size_t)(mB+rloc)*T_ + (T_-1))*S_ + cstar] = o;
        }
    }
  }
}

// ---------------- launcher ----------------
extern "C" void kernel_launch(void* const* d_in, const int* in_sizes, int n_in,
                              void* d_out, int out_size, void* d_ws, size_t ws_size,
                              hipStream_t stream)
{
  const float* x   = (const float*)d_in[0];
  const float* s0  = (const float*)d_in[1];
  const float* Wi0 = (const float*)d_in[2];
  const float* Wh0 = (const float*)d_in[3];
  const float* bi0 = (const float*)d_in[4];
  const float* bh0 = (const float*)d_in[5];
  const float* Wi1 = (const float*)d_in[6];
  const float* Wh1 = (const float*)d_in[7];
  const float* bi1 = (const float*)d_in[8];
  const float* bh1 = (const float*)d_in[9];
  const float* Wfc = (const float*)d_in[10];
  const float* bfc = (const float*)d_in[11];
  float* out = (float*)d_out;
  char* ws = (char*)d_ws;

  if (ws_size < WS_NEED) return;

  hipFuncSetAttribute(reinterpret_cast<const void*>(lstm_kernel),
                      hipFuncAttributeMaxDynamicSharedMemorySize, SMEM_BYTES);

  size_t nz = 32768/8 + 2*PLANE/8;
  zero_kernel<<<(int)((nz + 255)/256), 256, 0, stream>>>(ws);
  lstm_kernel<<<NG*WPG, 256, SMEM_BYTES, stream>>>(x, s0, Wi0, Wh0, bi0, bh0,
                                                   Wi1, Wh1, bi1, bh1, Wfc, bfc,
                                                   out, ws);
}

// Round 12
// 9425.372 us; speedup vs baseline: 3.3774x; 1.0777x over previous
//
#include <hip/hip_runtime.h>
#include <cstdint>
#include <cstddef>

// ---------------- types ----------------
typedef __bf16 bf16;
typedef _Float16 f16;
typedef __bf16 bf16x8 __attribute__((ext_vector_type(8)));
typedef _Float16 f16x8 __attribute__((ext_vector_type(8)));
typedef float  f32x4  __attribute__((ext_vector_type(4)));
typedef unsigned int uint2v __attribute__((ext_vector_type(2)));
typedef unsigned int uint4v __attribute__((ext_vector_type(4)));
typedef unsigned long long u64;

// ---------------- problem sizes ----------------
constexpr int B_=256, T_=512, H_=512, X_=128, S_=64, IN0=192;
constexpr int NG=2;              // batch groups
constexpr int MG=128;            // rows per group
constexpr int WPG=128;           // workgroups per group (slices)
constexpr int KB_X=4, KB_H=16, KB_S=2;
constexpr float LOSCL = 4096.0f, INV_LOSCL = 1.0f/4096.0f;

// ---------------- ws layout ----------------
constexpr size_t OFF_FLG=0;                           // 2*128*64 = 16384 B
constexpr size_t OFF_SC =32768;                       // [2][NG][64][128] f32 = 131072 B
constexpr size_t OFF_HP =OFF_SC+2ull*NG*64*128*4;     // 2 planes: H0H, H1H (f16)
constexpr size_t PLANE  =2ull*B_*H_*2;                // 524288 B each (double buffered)
constexpr size_t WS_NEED=OFF_HP+2*PLANE;              // ~1.3 MB

// ---------------- LDS ----------------
constexpr int NWX=KB_X*512;
constexpr int NWH=KB_H*512;
constexpr int NWS=KB_S*512;
constexpr int SMEM_BYTES = (2*NWX + 8*NWH + 2*NWS)*2
                         + 2*512*2 + 128*17*4 + 512*2 + 32*4;
static_assert(SMEM_BYTES == 155264, "lds size");
static_assert(SMEM_BYTES <= 160*1024, "lds limit");

// ---------------- asm VMEM: sc1 16B loads + FULL-DRAIN waits only ----------------
__device__ __forceinline__ uint4v ald16(const void* p) {       // sc1 16B
  uint4v r;
  asm volatile("global_load_dwordx4 %0, %1, off sc1"
               : "=&v"(r) : "v"(p) : "memory");
  return r;
}
#define VMW0 do { asm volatile("s_waitcnt vmcnt(0)" ::: "memory"); \
                  __builtin_amdgcn_sched_barrier(0); } while (0)
__device__ __forceinline__ f16x8 MKF(uint4v q) {
  union { uint4v q; f16x8 v; } u; u.q = q;
  return u.v;
}
__device__ __forceinline__ void astore8(void* p, uint2v v) {
  union { uint2v v; u64 q; } u; u.v = v;
  __hip_atomic_store((u64*)p, u.q, __ATOMIC_RELAXED, __HIP_MEMORY_SCOPE_AGENT);
}
__device__ __forceinline__ void astoref(float* p, float v) {
  __hip_atomic_store((unsigned*)p, __float_as_uint(v), __ATOMIC_RELAXED, __HIP_MEMORY_SCOPE_AGENT);
}
__device__ __forceinline__ float aloadf(const float* p) {
  return __uint_as_float(__hip_atomic_load((unsigned*)p, __ATOMIC_RELAXED, __HIP_MEMORY_SCOPE_AGENT));
}

// ---------------- helpers ----------------
__device__ __forceinline__ f32x4 mfmaB(bf16x8 a, bf16x8 b, f32x4 c) {
  return __builtin_amdgcn_mfma_f32_16x16x32_bf16(a, b, c, 0, 0, 0);
}
__device__ __forceinline__ f32x4 mfmaF(f16x8 a, f16x8 b, f32x4 c) {
  return __builtin_amdgcn_mfma_f32_16x16x32_f16(a, b, c, 0, 0, 0);
}
__device__ __forceinline__ f32x4 mfma3(bf16x8 ah, bf16x8 al, bf16x8 wh, bf16x8 wl, f32x4 c) {
  c = mfmaB(ah, wh, c);
  c = mfmaB(al, wh, c);
  c = mfmaB(ah, wl, c);
  return c;
}
__device__ __forceinline__ void split8p(const float* v, bf16x8& ah, bf16x8& al) {
  #pragma unroll
  for (int i=0;i<8;++i){ float f=v[i]; bf16 h=(bf16)f; ah[i]=h; al[i]=(bf16)(f-(float)h); }
}
__device__ __forceinline__ void split8v(f32x4 v0, f32x4 v1, bf16x8& ah, bf16x8& al) {
  #pragma unroll
  for (int i=0;i<4;++i){ float f=v0[i]; bf16 h=(bf16)f; ah[i]=h; al[i]=(bf16)(f-(float)h); }
  #pragma unroll
  for (int i=0;i<4;++i){ float f=v1[i]; bf16 h=(bf16)f; ah[4+i]=h; al[4+i]=(bf16)(f-(float)h); }
}
__device__ __forceinline__ float sigm(float v) { return 1.0f / (1.0f + __expf(-v)); }
__device__ __forceinline__ float tanhr(float v) {
  v = fminf(15.0f, fmaxf(-15.0f, v));
  float e = __expf(2.0f * v);
  return (e - 1.0f) / (e + 1.0f);
}

// All-scan group barrier: arrival on own padded flag line; every WG's first
// 128 threads poll all 128 flags directly (read-shared lines). Saves the
// leader+broadcast fabric hops. Poll volume ~43 loads/cy chip-wide << the
// ~242/cy transaction capacity measured in R6/R7, so no congestion hazard.
__device__ __forceinline__ void group_barrier(int* flg, int ns, int& phase) {
  ++phase;
  const int p = phase;
  asm volatile("s_waitcnt vmcnt(0)" ::: "memory");
  __syncthreads();
  if (threadIdx.x == 0)
    __hip_atomic_store(flg + ns*16, p, __ATOMIC_RELAXED, __HIP_MEMORY_SCOPE_AGENT);
  if (threadIdx.x < WPG) {
    while (__hip_atomic_load(flg + (int)threadIdx.x*16, __ATOMIC_RELAXED,
                             __HIP_MEMORY_SCOPE_AGENT) < p)
      __builtin_amdgcn_s_sleep(1);
  }
  __syncthreads();
}

// bf16 hi/lo pair pack (x and s chains)
__device__ void pack_slice(bf16* dH, bf16* dL, const float* src, int stride,
                           int koff, int nkb, int ns) {
  for (int p = (int)threadIdx.x; p < nkb*64; p += 256) {
    int ln = p & 63, kb = p >> 6;
    int c = ln & 15, k = kb*32 + ((ln>>4)<<3);
    int gcol = ((c>>2)<<9) + ns*4 + (c&3);
    const float* sp = src + (size_t)gcol*stride + koff + k;
    f32x4 v0 = *(const f32x4*)sp, v1 = *(const f32x4*)(sp+4);
    bf16x8 hv, lv;
    split8v(v0, v1, hv, lv);
    *(bf16x8*)(dH + p*8) = hv;
    *(bf16x8*)(dL + p*8) = lv;
  }
}
// f16 hi + 4096-scaled f16 lo pack (h chains)
__device__ void pack_slice_f16(f16* dH, f16* dL, const float* src, int stride,
                               int koff, int nkb, int ns) {
  for (int p = (int)threadIdx.x; p < nkb*64; p += 256) {
    int ln = p & 63, kb = p >> 6;
    int c = ln & 15, k = kb*32 + ((ln>>4)<<3);
    int gcol = ((c>>2)<<9) + ns*4 + (c&3);
    const float* sp = src + (size_t)gcol*stride + koff + k;
    f16x8 hv; f16x8 lv;
    #pragma unroll
    for (int i=0;i<8;++i) {
      float f = sp[i];
      f16 h = (f16)f;
      hv[i] = h;
      lv[i] = (f16)((f - (float)h) * LOSCL);
    }
    *(f16x8*)(dH + p*8) = hv;
    *(f16x8*)(dL + p*8) = lv;
  }
}

// ---------------- zero kernel ----------------
__global__ void zero_kernel(char* __restrict__ ws) {
  size_t i = (size_t)blockIdx.x*256 + threadIdx.x;
  size_t nsync = 32768/8;
  if (i < nsync) {
    __hip_atomic_store((u64*)(ws+OFF_FLG) + i, 0ull,
                       __ATOMIC_RELAXED, __HIP_MEMORY_SCOPE_AGENT);
    return;
  }
  i -= nsync;
  if (i < 2*PLANE/8)
    __hip_atomic_store((u64*)(ws+OFF_HP) + i, 0ull,
                       __ATOMIC_RELAXED, __HIP_MEMORY_SCOPE_AGENT);
}

// ---------------- persistent LSTM kernel ----------------
#define FRB(base, kb) (*(const bf16x8*)((base) + (((kb)*64 + lane)*8)))
#define FRF(base, kb) (*(const f16x8*)((base) + (((kb)*64 + lane)*8)))
#define WFC(base, kb) (*(const f16x8*)((base) + (kb)*32 + kq))

__global__ void __launch_bounds__(256, 1)
lstm_kernel(const float* __restrict__ x, const float* __restrict__ s0,
            const float* __restrict__ Wi0, const float* __restrict__ Wh0g,
            const float* __restrict__ bi0, const float* __restrict__ bh0,
            const float* __restrict__ Wi1g, const float* __restrict__ Wh1g,
            const float* __restrict__ bi1, const float* __restrict__ bh1,
            const float* __restrict__ Wfc, const float* __restrict__ bfc,
            float* __restrict__ out, char* __restrict__ ws)
{
  const int bid = blockIdx.x;
  const int g = bid & 1, ns = bid >> 1;
  const int tid = threadIdx.x;
  const int w = tid >> 6, lane = tid & 63, l15 = lane & 15;
  const int kq = (lane >> 4) << 3;
  const int mB = g * MG;
  const bool evenNs = (ns & 1) == 0;
  const int cstar = ns >> 1;
  int rowA[2];
  rowA[0] = mB + (w*2)*16 + l15;
  rowA[1] = rowA[0] + 16;

  int* flg = (int*)(ws + OFF_FLG) + g*128*16;
  float* SCbase = (float*)(ws + OFF_SC);
  f16* H0H_ = (f16*)(ws + OFF_HP);
  f16* H1H_ = (f16*)(ws + OFF_HP + PLANE);

  extern __shared__ char smem[];
  bf16* sWxH  = (bf16*)smem;
  bf16* sWxL  = sWxH + NWX;
  f16* sWh0H = (f16*)(sWxL + NWX);
  f16* sWh0L = sWh0H + NWH;
  f16* sWcbH = sWh0L + NWH;
  f16* sWcbL = sWcbH + NWH;
  f16* sWi1H = sWcbL + NWH;
  f16* sWi1L = sWi1H + NWH;
  f16* sWh1H = sWi1L + NWH;
  f16* sWh1L = sWh1H + NWH;
  bf16* sWsH  = (bf16*)(sWh1L + NWH);
  bf16* sWsL  = sWsH + NWS;
  f16* sWfcH = (f16*)(sWsL + NWS);
  f16* sWfcL = sWfcH + 512;
  float* sG   = (float*)(sWfcL + 512);
  f16*  sHh  = (f16*)(sG + 128*17);
  float* sB0  = (float*)(sHh + 512);
  float* sB1  = sB0 + 16;

  // ---- in-kernel weight packing ----
  pack_slice(sWxH,  sWxL,  Wi0,  IN0, 0,  KB_X, ns);
  pack_slice_f16(sWh0H, sWh0L, Wh0g, H_,  0,  KB_H, ns);
  pack_slice_f16(sWi1H, sWi1L, Wi1g, H_,  0,  KB_H, ns);
  pack_slice_f16(sWh1H, sWh1L, Wh1g, H_,  0,  KB_H, ns);
  pack_slice(sWsH,  sWsL,  Wi0,  IN0, X_, KB_S, ns);
  for (int p = tid; p < KB_H*64; p += 256) {                // Wcomb
    int ln = p & 63, kb = p >> 6;
    int c = ln & 15, k = kb*32 + ((ln>>4)<<3);
    int gcol = ((c>>2)<<9) + ns*4 + (c&3);
    const float* wis = Wi0 + (size_t)gcol*IN0 + X_;
    float a[8] = {0,0,0,0,0,0,0,0};
    for (int o = 0; o < S_; ++o) {
      float wv = wis[o];
      const float* fr = Wfc + (size_t)o*H_ + k;
      f32x4 f0 = *(const f32x4*)fr, f1 = *(const f32x4*)(fr+4);
      a[0]+=wv*f0[0]; a[1]+=wv*f0[1]; a[2]+=wv*f0[2]; a[3]+=wv*f0[3];
      a[4]+=wv*f1[0]; a[5]+=wv*f1[1]; a[6]+=wv*f1[2]; a[7]+=wv*f1[3];
    }
    f16x8 hv, lv;
    #pragma unroll
    for (int i=0;i<8;++i) {
      f16 h = (f16)a[i];
      hv[i] = h;
      lv[i] = (f16)((a[i] - (float)h) * LOSCL);
    }
    *(f16x8*)(sWcbH + p*8) = hv;
    *(f16x8*)(sWcbL + p*8) = lv;
  }
  for (int j = tid; j < H_; j += 256) {
    float f = Wfc[(size_t)cstar*H_ + j];
    f16 h = (f16)f;
    sWfcH[j] = h;
    sWfcL[j] = (f16)((f - (float)h) * LOSCL);
  }
  if (tid < 16) {
    int gcol = ((tid>>2)<<9) + ns*4 + (tid&3);
    sB0[tid] = bi0[gcol] + bh0[gcol];
    sB1[tid] = bi1[gcol] + bh1[gcol];
  }

  float bfcW;
  {
    int gcol = ((l15>>2)<<9) + ns*4 + (l15&3);
    const float* wr = Wi0 + (size_t)gcol*IN0 + X_;
    float bw = 0.f;
    for (int o = 0; o < S_; ++o) bw += bfc[o]*wr[o];
    bfcW = bw;
  }
  const float bfc_ns = bfc[cstar];

  float s_reg[2][16];
  #pragma unroll
  for (int mt=0;mt<2;++mt)
    #pragma unroll
    for (int kb=0;kb<KB_S;++kb)
      #pragma unroll
      for (int i=0;i<8;++i)
        s_reg[mt][kb*8+i] = s0[(size_t)rowA[mt]*S_ + kb*32 + kq + i];

  __syncthreads();

  f32x4 Gs[2];
  #pragma unroll
  for (int mt=0;mt<2;++mt) {
    bf16x8 sh0,sl0,sh1,sl1;
    split8p(&s_reg[mt][0], sh0, sl0);
    split8p(&s_reg[mt][8], sh1, sl1);
    f32x4 a = (f32x4){0.f,0.f,0.f,0.f};
    a = mfma3(sh0, sl0, FRB(sWsH,0), FRB(sWsL,0), a);
    a = mfma3(sh1, sl1, FRB(sWsH,1), FRB(sWsL,1), a);
    Gs[mt] = a;
  }

  // carried h0 fragments; zero at t=0
  uint4v c0q[2][16];
  #pragma unroll
  for (int mt=0;mt<2;++mt)
    #pragma unroll
    for (int kb=0;kb<16;++kb) c0q[mt][kb] = (uint4v){0,0,0,0};

  float c0s[2] = {0.f,0.f}, c1s[2] = {0.f,0.f};
  const int crow = tid >> 1;
  const int dbase = (tid & 1) << 1;
  int phase = 0;

  for (int t = 0; t < T_; ++t) {
    const int rd = t & 1, wr = rd ^ 1;
    const size_t rdo = (size_t)rd*B_*H_, wro = (size_t)wr*B_*H_;
    float* SCp = SCbase + ((size_t)rd*NG + g)*(64*128);

    f32x4 acc0[2], acc0L[2], acc1[2], acc1L[2], accF[2], accFL[2];
    {
      float addb = (t > 0) ? bfcW : 0.f;
      #pragma unroll
      for (int mt=0;mt<2;++mt) {
        #pragma unroll
        for (int r=0;r<4;++r) acc0[mt][r] = Gs[mt][r] + addb;
        acc0L[mt] = (f32x4){0.f,0.f,0.f,0.f};
        acc1[mt]  = (f32x4){0.f,0.f,0.f,0.f};
        acc1L[mt] = (f32x4){0.f,0.f,0.f,0.f};
        accF[mt]  = (f32x4){0.f,0.f,0.f,0.f};
        accFL[mt] = (f32x4){0.f,0.f,0.f,0.f};
      }
    }
    // x chain (compiler-managed cached loads)
    #pragma unroll
    for (int kb=0; kb<KB_X; ++kb) {
      bf16x8 wh = FRB(sWxH,kb), wl = FRB(sWxL,kb);
      #pragma unroll
      for (int mt=0;mt<2;++mt) {
        const float* xp = x + ((size_t)rowA[mt]*T_ + t)*X_ + kb*32 + kq;
        bf16x8 ah, al2;
        split8v(*(const f32x4*)xp, *(const f32x4*)(xp+4), ah, al2);
        acc0[mt] = mfma3(ah, al2, wh, wl, acc0[mt]);
      }
    }
    // ---- h1(t-1) ping-pong: issue half0; h0-carry chain hides flight ----
    uint4v q1a[2][8], q1b[2][8];
    #pragma unroll
    for (int mt=0;mt<2;++mt) {
      const f16* bA = H1H_ + rdo + (size_t)rowA[mt]*H_ + kq;
      #pragma unroll
      for (int k=0;k<8;++k) q1a[mt][k] = ald16(bA + k*32);
    }
    #pragma unroll
    for (int kb=0; kb<KB_H; ++kb) {          // h0-carry (register-only) under flight
      f16x8 wh = FRF(sWh0H,kb), wl = FRF(sWh0L,kb);
      #pragma unroll
      for (int mt=0;mt<2;++mt) {
        f16x8 a = MKF(c0q[mt][kb]);
        acc0[mt]  = mfmaF(a, wh, acc0[mt]);
        acc0L[mt] = mfmaF(a, wl, acc0L[mt]);
      }
    }
    VMW0;                                    // half0 ready
    #pragma unroll
    for (int mt=0;mt<2;++mt) {               // issue half1
      const f16* bA = H1H_ + rdo + (size_t)rowA[mt]*H_ + kq + 256;
      #pragma unroll
      for (int k=0;k<8;++k) q1b[mt][k] = ald16(bA + k*32);
    }
    #pragma unroll
    for (int k=0;k<8;++k) {                  // consume half0 under half1 flight
      const int kb = k;
      f16x8 cbh = FRF(sWcbH,kb), cbl = FRF(sWcbL,kb);
      f16x8 whh = FRF(sWh1H,kb), whl = FRF(sWh1L,kb);
      f16x8 fH  = WFC(sWfcH,kb),  fL = WFC(sWfcL,kb);
      #pragma unroll
      for (int mt=0;mt<2;++mt) {
        f16x8 a = MKF(q1a[mt][k]);
        acc0[mt]  = mfmaF(a, cbh, acc0[mt]);
        acc0L[mt] = mfmaF(a, cbl, acc0L[mt]);
        acc1[mt]  = mfmaF(a, whh, acc1[mt]);
        acc1L[mt] = mfmaF(a, whl, acc1L[mt]);
        accF[mt]  = mfmaF(a, fH,  accF[mt]);
        accFL[mt] = mfmaF(a, fL,  accFL[mt]);
      }
    }
    VMW0;                                    // half1 ready
    #pragma unroll
    for (int k=0;k<8;++k) {                  // consume half1
      const int kb = 8 + k;
      f16x8 cbh = FRF(sWcbH,kb), cbl = FRF(sWcbL,kb);
      f16x8 whh = FRF(sWh1H,kb), whl = FRF(sWh1L,kb);
      f16x8 fH  = WFC(sWfcH,kb),  fL = WFC(sWfcL,kb);
      #pragma unroll
      for (int mt=0;mt<2;++mt) {
        f16x8 a = MKF(q1b[mt][k]);
        acc0[mt]  = mfmaF(a, cbh, acc0[mt]);
        acc0L[mt] = mfmaF(a, cbl, acc0L[mt]);
        acc1[mt]  = mfmaF(a, whh, acc1[mt]);
        acc1L[mt] = mfmaF(a, whl, acc1L[mt]);
        accF[mt]  = mfmaF(a, fH,  accF[mt]);
        accFL[mt] = mfmaF(a, fL,  accFL[mt]);
      }
    }
    // fc write: out(t-1)[:, cstar]
    if (t > 0 && evenNs && l15 == 0) {
      #pragma unroll
      for (int mt=0;mt<2;++mt)
        #pragma unroll
        for (int r=0;r<4;++r) {
          int rloc = (w*2+mt)*16 + ((lane>>4)<<2) + r;
          float o = accF[mt][r] + accFL[mt][r]*INV_LOSCL + bfc_ns;
          out[((size_t)(mB+rloc)*T_ + (t-1))*S_ + cstar] = o;
          astoref(&SCp[cstar*128 + rloc], o);
        }
    }

    // bounce C -> (row, gatecol)
    #pragma unroll
    for (int mt=0;mt<2;++mt)
      #pragma unroll
      for (int r=0;r<4;++r)
        sG[((w*2+mt)*16 + ((lane>>4)<<2) + r)*17 + l15] =
            acc0[mt][r] + acc0L[mt][r]*INV_LOSCL;
    __syncthreads();
    {   // cell 0
      const float* gr = sG + crow*17;
      #pragma unroll
      for (int j=0;j<2;++j) {
        int d = dbase + j;
        float gi = gr[d]    + sB0[d];
        float gf = gr[4+d]  + sB0[4+d];
        float gg = gr[8+d]  + sB0[8+d];
        float go = gr[12+d] + sB0[12+d];
        c0s[j] = sigm(gf)*c0s[j] + sigm(gi)*tanhr(gg);
        sHh[crow*4+d] = (f16)(sigm(go)*tanhr(c0s[j]));
      }
    }
    __syncthreads();
    if (tid < MG) {
      size_t off = wro + (size_t)(mB+tid)*H_ + ns*4;
      astore8(H0H_ + off, *(const uint2v*)(sHh + tid*4));
    }
    group_barrier(flg, ns, phase);   // A: h0(t) + out columns visible

    // ---- s(t) update (compiler-managed sc1 loads), then h0 ping-pong ----
    if (t > 0) {
      const float* SCr = SCbase + ((size_t)rd*NG + g)*(64*128);
      #pragma unroll
      for (int mt=0;mt<2;++mt) {
        int rloc = (w*2+mt)*16 + l15;
        #pragma unroll
        for (int kb=0;kb<KB_S;++kb)
          #pragma unroll
          for (int i=0;i<8;++i)
            s_reg[mt][kb*8+i] += aloadf(&SCr[(kb*32+kq+i)*128 + rloc]);
      }
    }
    // issue h0(t) half0 into carry regs
    #pragma unroll
    for (int mt=0;mt<2;++mt) {
      const f16* bA = H0H_ + wro + (size_t)rowA[mt]*H_ + kq;
      #pragma unroll
      for (int k=0;k<8;++k) c0q[mt][k] = ald16(bA + k*32);
    }
    // fresh Gs (LDS+VALU only) under half0 flight
    #pragma unroll
    for (int mt=0;mt<2;++mt) {
      bf16x8 sh0,sl0,sh1,sl1;
      split8p(&s_reg[mt][0], sh0, sl0);
      split8p(&s_reg[mt][8], sh1, sl1);
      f32x4 a = (f32x4){0.f,0.f,0.f,0.f};
      a = mfma3(sh0, sl0, FRB(sWsH,0), FRB(sWsL,0), a);
      a = mfma3(sh1, sl1, FRB(sWsH,1), FRB(sWsL,1), a);
      Gs[mt] = a;
    }
    VMW0;                                    // half0 ready
    #pragma unroll
    for (int mt=0;mt<2;++mt) {               // issue half1
      const f16* bA = H0H_ + wro + (size_t)rowA[mt]*H_ + kq + 256;
      #pragma unroll
      for (int k=0;k<8;++k) c0q[mt][8+k] = ald16(bA + k*32);
    }
    #pragma unroll
    for (int kb=0; kb<8; ++kb) {             // consume half0 (Wi1) under flight
      f16x8 wh = FRF(sWi1H,kb), wl = FRF(sWi1L,kb);
      #pragma unroll
      for (int mt=0;mt<2;++mt) {
        f16x8 a = MKF(c0q[mt][kb]);
        acc1[mt]  = mfmaF(a, wh, acc1[mt]);
        acc1L[mt] = mfmaF(a, wl, acc1L[mt]);
      }
    }
    VMW0;                                    // half1 ready
    #pragma unroll
    for (int kb=8; kb<16; ++kb) {            // consume half1 (Wi1)
      f16x8 wh = FRF(sWi1H,kb), wl = FRF(sWi1L,kb);
      #pragma unroll
      for (int mt=0;mt<2;++mt) {
        f16x8 a = MKF(c0q[mt][kb]);
        acc1[mt]  = mfmaF(a, wh, acc1[mt]);
        acc1L[mt] = mfmaF(a, wl, acc1L[mt]);
      }
    }

    #pragma unroll
    for (int mt=0;mt<2;++mt)
      #pragma unroll
      for (int r=0;r<4;++r)
        sG[((w*2+mt)*16 + ((lane>>4)<<2) + r)*17 + l15] =
            acc1[mt][r] + acc1L[mt][r]*INV_LOSCL;
    __syncthreads();
    {   // cell 1
      const float* gr = sG + crow*17;
      #pragma unroll
      for (int j=0;j<2;++j) {
        int d = dbase + j;
        float gi = gr[d]    + sB1[d];
        float gf = gr[4+d]  + sB1[4+d];
        float gg = gr[8+d]  + sB1[8+d];
        float go = gr[12+d] + sB1[12+d];
        c1s[j] = sigm(gf)*c1s[j] + sigm(gi)*tanhr(gg);
        sHh[crow*4+d] = (f16)(sigm(go)*tanhr(c1s[j]));
      }
    }
    __syncthreads();
    if (tid < MG) {
      size_t off = wro + (size_t)(mB+tid)*H_ + ns*4;
      astore8(H1H_ + off, *(const uint2v*)(sHh + tid*4));
    }
    group_barrier(flg, ns, phase);   // B: h1(t) visible
  }

  // ---- epilogue: out(T-1) via fc-MFMA on h1(T-1) (buffer 0) ----
  if (evenNs) {
    f32x4 accF[2], accFL[2];
    #pragma unroll
    for (int mt=0;mt<2;++mt) {
      accF[mt]  = (f32x4){0.f,0.f,0.f,0.f};
      accFL[mt] = (f32x4){0.f,0.f,0.f,0.f};
    }
    uint4v q[2][16];
    #pragma unroll
    for (int mt=0;mt<2;++mt) {
      const f16* bA = H1H_ + (size_t)rowA[mt]*H_ + kq;
      #pragma unroll
      for (int kb=0; kb<16; ++kb) q[mt][kb] = ald16(bA + kb*32);
    }
    VMW0;
    #pragma unroll
    for (int kb=0; kb<16; ++kb) {
      f16x8 fH = WFC(sWfcH,kb), fL = WFC(sWfcL,kb);
      #pragma unroll
      for (int mt=0;mt<2;++mt) {
        f16x8 a = MKF(q[mt][kb]);
        accF[mt]  = mfmaF(a, fH, accF[mt]);
        accFL[mt] = mfmaF(a, fL, accFL[mt]);
      }
    }
    if (l15 == 0) {
      #pragma unroll
      for (int mt=0;mt<2;++mt)
        #pragma unroll
        for (int r=0;r<4;++r) {
          int rloc = (w*2+mt)*16 + ((lane>>4)<<2) + r;
          float o = accF[mt][r] + accFL[mt][r]*INV_LOSCL + bfc_ns;
          out[((size_t)(mB+rloc)*T_ + (T_-1))*S_ + cstar] = o;
        }
    }
  }
}

// ---------------- launcher ----------------
extern "C" void kernel_launch(void* const* d_in, const int* in_sizes, int n_in,
                              void* d_out, int out_size, void* d_ws, size_t ws_size,
                              hipStream_t stream)
{
  const float* x   = (const float*)d_in[0];
  const float* s0  = (const float*)d_in[1];
  const float* Wi0 = (const float*)d_in[2];
  const float* Wh0 = (const float*)d_in[3];
  const float* bi0 = (const float*)d_in[4];
  const float* bh0 = (const float*)d_in[5];
  const float* Wi1 = (const float*)d_in[6];
  const float* Wh1 = (const float*)d_in[7];
  const float* bi1 = (const float*)d_in[8];
  const float* bh1 = (const float*)d_in[9];
  const float* Wfc = (const float*)d_in[10];
  const float* bfc = (const float*)d_in[11];
  float* out = (float*)d_out;
  char* ws = (char*)d_ws;

  if (ws_size < WS_NEED) return;

  hipFuncSetAttribute(reinterpret_cast<const void*>(lstm_kernel),
                      hipFuncAttributeMaxDynamicSharedMemorySize, SMEM_BYTES);

  size_t nz = 32768/8 + 2*PLANE/8;
  zero_kernel<<<(int)((nz + 255)/256), 256, 0, stream>>>(ws);
  lstm_kernel<<<NG*WPG, 256, SMEM_BYTES, stream>>>(x, s0, Wi0, Wh0, bi0, bh0,
                                                   Wi1, Wh1, bi1, bh1, Wfc, bfc,
                                                   out, ws);
}

// Round 13
// 9371.136 us; speedup vs baseline: 3.3969x; 1.0058x over previous
//
#include <hip/hip_runtime.h>
#include <cstdint>
#include <cstddef>

// ---------------- types ----------------
typedef __bf16 bf16;
typedef _Float16 f16;
typedef __bf16 bf16x8 __attribute__((ext_vector_type(8)));
typedef _Float16 f16x8 __attribute__((ext_vector_type(8)));
typedef float  f32x4  __attribute__((ext_vector_type(4)));
typedef unsigned int uint2v __attribute__((ext_vector_type(2)));
typedef unsigned int uint4v __attribute__((ext_vector_type(4)));
typedef unsigned long long u64;

// ---------------- problem sizes ----------------
constexpr int B_=256, T_=512, H_=512, X_=128, S_=64, IN0=192;
constexpr int NG=2;              // batch groups
constexpr int MG=128;            // rows per group
constexpr int WPG=128;           // workgroups per group (slices)
constexpr int KB_X=4, KB_H=16, KB_S=2;
constexpr float LOSCL = 4096.0f, INV_LOSCL = 1.0f/4096.0f;

// ---------------- ws layout ----------------
constexpr size_t OFF_FLG=0;                           // 2*128*64 = 16384 B
constexpr size_t OFF_SC =32768;                       // [2][NG][64][128] f32 = 131072 B
constexpr size_t OFF_HP =OFF_SC+2ull*NG*64*128*4;     // 2 planes: H0H, H1H (f16)
constexpr size_t PLANE  =2ull*B_*H_*2;                // 524288 B each (double buffered)
constexpr size_t WS_NEED=OFF_HP+2*PLANE;              // ~1.3 MB

// ---------------- LDS ----------------
constexpr int NWX=KB_X*512;
constexpr int NWH=KB_H*512;
constexpr int NWS=KB_S*512;
constexpr int SMEM_BYTES = (2*NWX + 8*NWH + 2*NWS)*2
                         + 2*512*2 + 128*17*4 + 512*2 + 32*4;
static_assert(SMEM_BYTES == 155264, "lds size");
static_assert(SMEM_BYTES <= 160*1024, "lds limit");

// ---------------- asm VMEM ----------------
__device__ __forceinline__ uint4v ald16(const void* p) {       // sc1 16B
  uint4v r;
  asm volatile("global_load_dwordx4 %0, %1, off sc1"
               : "=&v"(r) : "v"(p) : "memory");
  return r;
}
#define VMW0 do { asm volatile("s_waitcnt vmcnt(0)" ::: "memory"); \
                  __builtin_amdgcn_sched_barrier(0); } while (0)
#define VMW16 do { asm volatile("s_waitcnt vmcnt(16)" ::: "memory"); \
                   __builtin_amdgcn_sched_barrier(0); } while (0)
__device__ __forceinline__ f16x8 MKF(uint4v q) {
  union { uint4v q; f16x8 v; } u; u.q = q;
  return u.v;
}
__device__ __forceinline__ void astore8(void* p, uint2v v) {
  union { uint2v v; u64 q; } u; u.v = v;
  __hip_atomic_store((u64*)p, u.q, __ATOMIC_RELAXED, __HIP_MEMORY_SCOPE_AGENT);
}
__device__ __forceinline__ void astoref(float* p, float v) {
  __hip_atomic_store((unsigned*)p, __float_as_uint(v), __ATOMIC_RELAXED, __HIP_MEMORY_SCOPE_AGENT);
}
__device__ __forceinline__ float aloadf(const float* p) {
  return __uint_as_float(__hip_atomic_load((unsigned*)p, __ATOMIC_RELAXED, __HIP_MEMORY_SCOPE_AGENT));
}

// ---------------- helpers ----------------
__device__ __forceinline__ f32x4 mfmaB(bf16x8 a, bf16x8 b, f32x4 c) {
  return __builtin_amdgcn_mfma_f32_16x16x32_bf16(a, b, c, 0, 0, 0);
}
__device__ __forceinline__ f32x4 mfmaF(f16x8 a, f16x8 b, f32x4 c) {
  return __builtin_amdgcn_mfma_f32_16x16x32_f16(a, b, c, 0, 0, 0);
}
__device__ __forceinline__ f32x4 mfma3(bf16x8 ah, bf16x8 al, bf16x8 wh, bf16x8 wl, f32x4 c) {
  c = mfmaB(ah, wh, c);
  c = mfmaB(al, wh, c);
  c = mfmaB(ah, wl, c);
  return c;
}
__device__ __forceinline__ void split8p(const float* v, bf16x8& ah, bf16x8& al) {
  #pragma unroll
  for (int i=0;i<8;++i){ float f=v[i]; bf16 h=(bf16)f; ah[i]=h; al[i]=(bf16)(f-(float)h); }
}
__device__ __forceinline__ void split8v(f32x4 v0, f32x4 v1, bf16x8& ah, bf16x8& al) {
  #pragma unroll
  for (int i=0;i<4;++i){ float f=v0[i]; bf16 h=(bf16)f; ah[i]=h; al[i]=(bf16)(f-(float)h); }
  #pragma unroll
  for (int i=0;i<4;++i){ float f=v1[i]; bf16 h=(bf16)f; ah[4+i]=h; al[4+i]=(bf16)(f-(float)h); }
}
__device__ __forceinline__ float sigm(float v) { return 1.0f / (1.0f + __expf(-v)); }
__device__ __forceinline__ float tanhr(float v) {
  v = fminf(15.0f, fmaxf(-15.0f, v));
  float e = __expf(2.0f * v);
  return (e - 1.0f) / (e + 1.0f);
}

// All-scan group barrier, busy-spin (no s_sleep: detect latency = one load RT)
__device__ __forceinline__ void group_barrier(int* flg, int ns, int& phase) {
  ++phase;
  const int p = phase;
  asm volatile("s_waitcnt vmcnt(0)" ::: "memory");
  __syncthreads();
  if (threadIdx.x == 0)
    __hip_atomic_store(flg + ns*16, p, __ATOMIC_RELAXED, __HIP_MEMORY_SCOPE_AGENT);
  if (threadIdx.x < WPG) {
    while (__hip_atomic_load(flg + (int)threadIdx.x*16, __ATOMIC_RELAXED,
                             __HIP_MEMORY_SCOPE_AGENT) < p) { }
  }
  __syncthreads();
}

// bf16 hi/lo pair pack (x and s chains)
__device__ void pack_slice(bf16* dH, bf16* dL, const float* src, int stride,
                           int koff, int nkb, int ns) {
  for (int p = (int)threadIdx.x; p < nkb*64; p += 256) {
    int ln = p & 63, kb = p >> 6;
    int c = ln & 15, k = kb*32 + ((ln>>4)<<3);
    int gcol = ((c>>2)<<9) + ns*4 + (c&3);
    const float* sp = src + (size_t)gcol*stride + koff + k;
    f32x4 v0 = *(const f32x4*)sp, v1 = *(const f32x4*)(sp+4);
    bf16x8 hv, lv;
    split8v(v0, v1, hv, lv);
    *(bf16x8*)(dH + p*8) = hv;
    *(bf16x8*)(dL + p*8) = lv;
  }
}
// f16 hi + 4096-scaled f16 lo pack (h chains)
__device__ void pack_slice_f16(f16* dH, f16* dL, const float* src, int stride,
                               int koff, int nkb, int ns) {
  for (int p = (int)threadIdx.x; p < nkb*64; p += 256) {
    int ln = p & 63, kb = p >> 6;
    int c = ln & 15, k = kb*32 + ((ln>>4)<<3);
    int gcol = ((c>>2)<<9) + ns*4 + (c&3);
    const float* sp = src + (size_t)gcol*stride + koff + k;
    f16x8 hv; f16x8 lv;
    #pragma unroll
    for (int i=0;i<8;++i) {
      float f = sp[i];
      f16 h = (f16)f;
      hv[i] = h;
      lv[i] = (f16)((f - (float)h) * LOSCL);
    }
    *(f16x8*)(dH + p*8) = hv;
    *(f16x8*)(dL + p*8) = lv;
  }
}

// ---------------- zero kernel ----------------
__global__ void zero_kernel(char* __restrict__ ws) {
  size_t i = (size_t)blockIdx.x*256 + threadIdx.x;
  size_t nsync = 32768/8;
  if (i < nsync) {
    __hip_atomic_store((u64*)(ws+OFF_FLG) + i, 0ull,
                       __ATOMIC_RELAXED, __HIP_MEMORY_SCOPE_AGENT);
    return;
  }
  i -= nsync;
  if (i < 2*PLANE/8)
    __hip_atomic_store((u64*)(ws+OFF_HP) + i, 0ull,
                       __ATOMIC_RELAXED, __HIP_MEMORY_SCOPE_AGENT);
}

// ---------------- persistent LSTM kernel ----------------
#define FRB(base, kb) (*(const bf16x8*)((base) + (((kb)*64 + lane)*8)))
#define FRF(base, kb) (*(const f16x8*)((base) + (((kb)*64 + lane)*8)))
#define WFC(base, kb) (*(const f16x8*)((base) + (kb)*32 + kq))

__global__ void __launch_bounds__(256, 1)
lstm_kernel(const float* __restrict__ x, const float* __restrict__ s0,
            const float* __restrict__ Wi0, const float* __restrict__ Wh0g,
            const float* __restrict__ bi0, const float* __restrict__ bh0,
            const float* __restrict__ Wi1g, const float* __restrict__ Wh1g,
            const float* __restrict__ bi1, const float* __restrict__ bh1,
            const float* __restrict__ Wfc, const float* __restrict__ bfc,
            float* __restrict__ out, char* __restrict__ ws)
{
  const int bid = blockIdx.x;
  const int g = bid & 1, ns = bid >> 1;
  const int tid = threadIdx.x;
  const int w = tid >> 6, lane = tid & 63, l15 = lane & 15;
  const int kq = (lane >> 4) << 3;
  const int mB = g * MG;
  const bool evenNs = (ns & 1) == 0;
  const int cstar = ns >> 1;
  int rowA[2];
  rowA[0] = mB + (w*2)*16 + l15;
  rowA[1] = rowA[0] + 16;

  int* flg = (int*)(ws + OFF_FLG) + g*128*16;
  float* SCbase = (float*)(ws + OFF_SC);
  f16* H0H_ = (f16*)(ws + OFF_HP);
  f16* H1H_ = (f16*)(ws + OFF_HP + PLANE);

  extern __shared__ char smem[];
  bf16* sWxH  = (bf16*)smem;
  bf16* sWxL  = sWxH + NWX;
  f16* sWh0H = (f16*)(sWxL + NWX);
  f16* sWh0L = sWh0H + NWH;
  f16* sWcbH = sWh0L + NWH;
  f16* sWcbL = sWcbH + NWH;
  f16* sWi1H = sWcbL + NWH;
  f16* sWi1L = sWi1H + NWH;
  f16* sWh1H = sWi1L + NWH;
  f16* sWh1L = sWh1H + NWH;
  bf16* sWsH  = (bf16*)(sWh1L + NWH);
  bf16* sWsL  = sWsH + NWS;
  f16* sWfcH = (f16*)(sWsL + NWS);
  f16* sWfcL = sWfcH + 512;
  float* sG   = (float*)(sWfcL + 512);
  f16*  sHh  = (f16*)(sG + 128*17);
  float* sB0  = (float*)(sHh + 512);
  float* sB1  = sB0 + 16;

  // ---- in-kernel weight packing ----
  pack_slice(sWxH,  sWxL,  Wi0,  IN0, 0,  KB_X, ns);
  pack_slice_f16(sWh0H, sWh0L, Wh0g, H_,  0,  KB_H, ns);
  pack_slice_f16(sWi1H, sWi1L, Wi1g, H_,  0,  KB_H, ns);
  pack_slice_f16(sWh1H, sWh1L, Wh1g, H_,  0,  KB_H, ns);
  pack_slice(sWsH,  sWsL,  Wi0,  IN0, X_, KB_S, ns);
  for (int p = tid; p < KB_H*64; p += 256) {                // Wcomb
    int ln = p & 63, kb = p >> 6;
    int c = ln & 15, k = kb*32 + ((ln>>4)<<3);
    int gcol = ((c>>2)<<9) + ns*4 + (c&3);
    const float* wis = Wi0 + (size_t)gcol*IN0 + X_;
    float a[8] = {0,0,0,0,0,0,0,0};
    for (int o = 0; o < S_; ++o) {
      float wv = wis[o];
      const float* fr = Wfc + (size_t)o*H_ + k;
      f32x4 f0 = *(const f32x4*)fr, f1 = *(const f32x4*)(fr+4);
      a[0]+=wv*f0[0]; a[1]+=wv*f0[1]; a[2]+=wv*f0[2]; a[3]+=wv*f0[3];
      a[4]+=wv*f1[0]; a[5]+=wv*f1[1]; a[6]+=wv*f1[2]; a[7]+=wv*f1[3];
    }
    f16x8 hv, lv;
    #pragma unroll
    for (int i=0;i<8;++i) {
      f16 h = (f16)a[i];
      hv[i] = h;
      lv[i] = (f16)((a[i] - (float)h) * LOSCL);
    }
    *(f16x8*)(sWcbH + p*8) = hv;
    *(f16x8*)(sWcbL + p*8) = lv;
  }
  for (int j = tid; j < H_; j += 256) {
    float f = Wfc[(size_t)cstar*H_ + j];
    f16 h = (f16)f;
    sWfcH[j] = h;
    sWfcL[j] = (f16)((f - (float)h) * LOSCL);
  }
  if (tid < 16) {
    int gcol = ((tid>>2)<<9) + ns*4 + (tid&3);
    sB0[tid] = bi0[gcol] + bh0[gcol];
    sB1[tid] = bi1[gcol] + bh1[gcol];
  }

  float bfcW;
  {
    int gcol = ((l15>>2)<<9) + ns*4 + (l15&3);
    const float* wr = Wi0 + (size_t)gcol*IN0 + X_;
    float bw = 0.f;
    for (int o = 0; o < S_; ++o) bw += bfc[o]*wr[o];
    bfcW = bw;
  }
  const float bfc_ns = bfc[cstar];

  float s_reg[2][16];
  #pragma unroll
  for (int mt=0;mt<2;++mt)
    #pragma unroll
    for (int kb=0;kb<KB_S;++kb)
      #pragma unroll
      for (int i=0;i<8;++i)
        s_reg[mt][kb*8+i] = s0[(size_t)rowA[mt]*S_ + kb*32 + kq + i];

  __syncthreads();

  f32x4 Gs[2];
  #pragma unroll
  for (int mt=0;mt<2;++mt) {
    bf16x8 sh0,sl0,sh1,sl1;
    split8p(&s_reg[mt][0], sh0, sl0);
    split8p(&s_reg[mt][8], sh1, sl1);
    f32x4 a = (f32x4){0.f,0.f,0.f,0.f};
    a = mfma3(sh0, sl0, FRB(sWsH,0), FRB(sWsL,0), a);
    a = mfma3(sh1, sl1, FRB(sWsH,1), FRB(sWsL,1), a);
    Gs[mt] = a;
  }

  // carried h0 fragments; zero at t=0
  uint4v c0q[2][16];
  #pragma unroll
  for (int mt=0;mt<2;++mt)
    #pragma unroll
    for (int kb=0;kb<16;++kb) c0q[mt][kb] = (uint4v){0,0,0,0};

  float c0s[2] = {0.f,0.f}, c1s[2] = {0.f,0.f};
  const int crow = tid >> 1;
  const int dbase = (tid & 1) << 1;
  int phase = 0;

  for (int t = 0; t < T_; ++t) {
    const int rd = t & 1, wr = rd ^ 1;
    const size_t rdo = (size_t)rd*B_*H_, wro = (size_t)wr*B_*H_;
    float* SCp = SCbase + ((size_t)rd*NG + g)*(64*128);

    f32x4 acc0[2], acc0L[2], acc1[2], acc1L[2], accF[2], accFL[2];
    {
      float addb = (t > 0) ? bfcW : 0.f;
      #pragma unroll
      for (int mt=0;mt<2;++mt) {
        #pragma unroll
        for (int r=0;r<4;++r) acc0[mt][r] = Gs[mt][r] + addb;
        acc0L[mt] = (f32x4){0.f,0.f,0.f,0.f};
        acc1[mt]  = (f32x4){0.f,0.f,0.f,0.f};
        acc1L[mt] = (f32x4){0.f,0.f,0.f,0.f};
        accF[mt]  = (f32x4){0.f,0.f,0.f,0.f};
        accFL[mt] = (f32x4){0.f,0.f,0.f,0.f};
      }
    }
    // x chain (compiler-managed cached loads; finishes before asm issues)
    #pragma unroll
    for (int kb=0; kb<KB_X; ++kb) {
      bf16x8 wh = FRB(sWxH,kb), wl = FRB(sWxL,kb);
      #pragma unroll
      for (int mt=0;mt<2;++mt) {
        const float* xp = x + ((size_t)rowA[mt]*T_ + t)*X_ + kb*32 + kq;
        bf16x8 ah, al2;
        split8v(*(const f32x4*)xp, *(const f32x4*)(xp+4), ah, al2);
        acc0[mt] = mfma3(ah, al2, wh, wl, acc0[mt]);
      }
    }
    __builtin_amdgcn_sched_barrier(0);       // pin x-loads/waits before asm window
    // ---- h1(t-1) pipelined ping-pong: a-issue, hide, b-issue, vmcnt(16) ----
    uint4v q1a[2][8], q1b[2][8];
    #pragma unroll
    for (int mt=0;mt<2;++mt) {
      const f16* bA = H1H_ + rdo + (size_t)rowA[mt]*H_ + kq;
      #pragma unroll
      for (int k=0;k<8;++k) q1a[mt][k] = ald16(bA + k*32);
    }
    #pragma unroll
    for (int kb=0; kb<KB_H; ++kb) {          // h0-carry (reg/LDS-only) hides half0
      f16x8 wh = FRF(sWh0H,kb), wl = FRF(sWh0L,kb);
      #pragma unroll
      for (int mt=0;mt<2;++mt) {
        f16x8 a = MKF(c0q[mt][kb]);
        acc0[mt]  = mfmaF(a, wh, acc0[mt]);
        acc0L[mt] = mfmaF(a, wl, acc0L[mt]);
      }
    }
    #pragma unroll
    for (int mt=0;mt<2;++mt) {               // issue half1 BEFORE half0 wait
      const f16* bA = H1H_ + rdo + (size_t)rowA[mt]*H_ + kq + 256;
      #pragma unroll
      for (int k=0;k<8;++k) q1b[mt][k] = ald16(bA + k*32);
    }
    VMW16;                                   // half0 ready (16 of 32 remain)
    #pragma unroll
    for (int k=0;k<8;++k) {                  // consume half0 under half1 flight
      const int kb = k;
      f16x8 cbh = FRF(sWcbH,kb), cbl = FRF(sWcbL,kb);
      f16x8 whh = FRF(sWh1H,kb), whl = FRF(sWh1L,kb);
      f16x8 fH  = WFC(sWfcH,kb),  fL = WFC(sWfcL,kb);
      #pragma unroll
      for (int mt=0;mt<2;++mt) {
        f16x8 a = MKF(q1a[mt][k]);
        acc0[mt]  = mfmaF(a, cbh, acc0[mt]);
        acc0L[mt] = mfmaF(a, cbl, acc0L[mt]);
        acc1[mt]  = mfmaF(a, whh, acc1[mt]);
        acc1L[mt] = mfmaF(a, whl, acc1L[mt]);
        accF[mt]  = mfmaF(a, fH,  accF[mt]);
        accFL[mt] = mfmaF(a, fL,  accFL[mt]);
      }
    }
    VMW0;                                    // half1 ready
    #pragma unroll
    for (int k=0;k<8;++k) {                  // consume half1
      const int kb = 8 + k;
      f16x8 cbh = FRF(sWcbH,kb), cbl = FRF(sWcbL,kb);
      f16x8 whh = FRF(sWh1H,kb), whl = FRF(sWh1L,kb);
      f16x8 fH  = WFC(sWfcH,kb),  fL = WFC(sWfcL,kb);
      #pragma unroll
      for (int mt=0;mt<2;++mt) {
        f16x8 a = MKF(q1b[mt][k]);
        acc0[mt]  = mfmaF(a, cbh, acc0[mt]);
        acc0L[mt] = mfmaF(a, cbl, acc0L[mt]);
        acc1[mt]  = mfmaF(a, whh, acc1[mt]);
        acc1L[mt] = mfmaF(a, whl, acc1L[mt]);
        accF[mt]  = mfmaF(a, fH,  accF[mt]);
        accFL[mt] = mfmaF(a, fL,  accFL[mt]);
      }
    }
    // fc write: out(t-1)[:, cstar]
    if (t > 0 && evenNs && l15 == 0) {
      #pragma unroll
      for (int mt=0;mt<2;++mt)
        #pragma unroll
        for (int r=0;r<4;++r) {
          int rloc = (w*2+mt)*16 + ((lane>>4)<<2) + r;
          float o = accF[mt][r] + accFL[mt][r]*INV_LOSCL + bfc_ns;
          out[((size_t)(mB+rloc)*T_ + (t-1))*S_ + cstar] = o;
          astoref(&SCp[cstar*128 + rloc], o);
        }
    }

    // bounce C -> (row, gatecol)
    #pragma unroll
    for (int mt=0;mt<2;++mt)
      #pragma unroll
      for (int r=0;r<4;++r)
        sG[((w*2+mt)*16 + ((lane>>4)<<2) + r)*17 + l15] =
            acc0[mt][r] + acc0L[mt][r]*INV_LOSCL;
    __syncthreads();
    {   // cell 0
      const float* gr = sG + crow*17;
      #pragma unroll
      for (int j=0;j<2;++j) {
        int d = dbase + j;
        float gi = gr[d]    + sB0[d];
        float gf = gr[4+d]  + sB0[4+d];
        float gg = gr[8+d]  + sB0[8+d];
        float go = gr[12+d] + sB0[12+d];
        c0s[j] = sigm(gf)*c0s[j] + sigm(gi)*tanhr(gg);
        sHh[crow*4+d] = (f16)(sigm(go)*tanhr(c0s[j]));
      }
    }
    __syncthreads();
    if (tid < MG) {
      size_t off = wro + (size_t)(mB+tid)*H_ + ns*4;
      astore8(H0H_ + off, *(const uint2v*)(sHh + tid*4));
    }
    group_barrier(flg, ns, phase);   // A: h0(t) + out columns visible

    // ---- s(t) update (compiler sc1 loads, pinned), then h0 pipelined ----
    if (t > 0) {
      const float* SCr = SCbase + ((size_t)rd*NG + g)*(64*128);
      #pragma unroll
      for (int mt=0;mt<2;++mt) {
        int rloc = (w*2+mt)*16 + l15;
        #pragma unroll
        for (int kb=0;kb<KB_S;++kb)
          #pragma unroll
          for (int i=0;i<8;++i)
            s_reg[mt][kb*8+i] += aloadf(&SCr[(kb*32+kq+i)*128 + rloc]);
      }
    }
    __builtin_amdgcn_sched_barrier(0);       // pin SC loads/waits before asm window
    // issue h0(t) half0 into carry regs
    #pragma unroll
    for (int mt=0;mt<2;++mt) {
      const f16* bA = H0H_ + wro + (size_t)rowA[mt]*H_ + kq;
      #pragma unroll
      for (int k=0;k<8;++k) c0q[mt][k] = ald16(bA + k*32);
    }
    // fresh Gs (LDS+VALU+MFMA only) under half0 flight
    #pragma unroll
    for (int mt=0;mt<2;++mt) {
      bf16x8 sh0,sl0,sh1,sl1;
      split8p(&s_reg[mt][0], sh0, sl0);
      split8p(&s_reg[mt][8], sh1, sl1);
      f32x4 a = (f32x4){0.f,0.f,0.f,0.f};
      a = mfma3(sh0, sl0, FRB(sWsH,0), FRB(sWsL,0), a);
      a = mfma3(sh1, sl1, FRB(sWsH,1), FRB(sWsL,1), a);
      Gs[mt] = a;
    }
    #pragma unroll
    for (int mt=0;mt<2;++mt) {               // issue half1 BEFORE half0 wait
      const f16* bA = H0H_ + wro + (size_t)rowA[mt]*H_ + kq + 256;
      #pragma unroll
      for (int k=0;k<8;++k) c0q[mt][8+k] = ald16(bA + k*32);
    }
    VMW16;                                   // half0 ready
    #pragma unroll
    for (int kb=0; kb<8; ++kb) {             // consume half0 (Wi1) under flight
      f16x8 wh = FRF(sWi1H,kb), wl = FRF(sWi1L,kb);
      #pragma unroll
      for (int mt=0;mt<2;++mt) {
        f16x8 a = MKF(c0q[mt][kb]);
        acc1[mt]  = mfmaF(a, wh, acc1[mt]);
        acc1L[mt] = mfmaF(a, wl, acc1L[mt]);
      }
    }
    VMW0;                                    // half1 ready
    #pragma unroll
    for (int kb=8; kb<16; ++kb) {            // consume half1 (Wi1)
      f16x8 wh = FRF(sWi1H,kb), wl = FRF(sWi1L,kb);
      #pragma unroll
      for (int mt=0;mt<2;++mt) {
        f16x8 a = MKF(c0q[mt][kb]);
        acc1[mt]  = mfmaF(a, wh, acc1[mt]);
        acc1L[mt] = mfmaF(a, wl, acc1L[mt]);
      }
    }

    #pragma unroll
    for (int mt=0;mt<2;++mt)
      #pragma unroll
      for (int r=0;r<4;++r)
        sG[((w*2+mt)*16 + ((lane>>4)<<2) + r)*17 + l15] =
            acc1[mt][r] + acc1L[mt][r]*INV_LOSCL;
    __syncthreads();
    {   // cell 1
      const float* gr = sG + crow*17;
      #pragma unroll
      for (int j=0;j<2;++j) {
        int d = dbase + j;
        float gi = gr[d]    + sB1[d];
        float gf = gr[4+d]  + sB1[4+d];
        float gg = gr[8+d]  + sB1[8+d];
        float go = gr[12+d] + sB1[12+d];
        c1s[j] = sigm(gf)*c1s[j] + sigm(gi)*tanhr(gg);
        sHh[crow*4+d] = (f16)(sigm(go)*tanhr(c1s[j]));
      }
    }
    __syncthreads();
    if (tid < MG) {
      size_t off = wro + (size_t)(mB+tid)*H_ + ns*4;
      astore8(H1H_ + off, *(const uint2v*)(sHh + tid*4));
    }
    group_barrier(flg, ns, phase);   // B: h1(t) visible
  }

  // ---- epilogue: out(T-1) via fc-MFMA on h1(T-1) (buffer 0) ----
  if (evenNs) {
    f32x4 accF[2], accFL[2];
    #pragma unroll
    for (int mt=0;mt<2;++mt) {
      accF[mt]  = (f32x4){0.f,0.f,0.f,0.f};
      accFL[mt] = (f32x4){0.f,0.f,0.f,0.f};
    }
    uint4v q[2][16];
    #pragma unroll
    for (int mt=0;mt<2;++mt) {
      const f16* bA = H1H_ + (size_t)rowA[mt]*H_ + kq;
      #pragma unroll
      for (int kb=0; kb<16; ++kb) q[mt][kb] = ald16(bA + kb*32);
    }
    VMW0;
    #pragma unroll
    for (int kb=0; kb<16; ++kb) {
      f16x8 fH = WFC(sWfcH,kb), fL = WFC(sWfcL,kb);
      #pragma unroll
      for (int mt=0;mt<2;++mt) {
        f16x8 a = MKF(q[mt][kb]);
        accF[mt]  = mfmaF(a, fH, accF[mt]);
        accFL[mt] = mfmaF(a, fL, accFL[mt]);
      }
    }
    if (l15 == 0) {
      #pragma unroll
      for (int mt=0;mt<2;++mt)
        #pragma unroll
        for (int r=0;r<4;++r) {
          int rloc = (w*2+mt)*16 + ((lane>>4)<<2) + r;
          float o = accF[mt][r] + accFL[mt][r]*INV_LOSCL + bfc_ns;
          out[((size_t)(mB+rloc)*T_ + (T_-1))*S_ + cstar] = o;
        }
    }
  }
}

// ---------------- launcher ----------------
extern "C" void kernel_launch(void* const* d_in, const int* in_sizes, int n_in,
                              void* d_out, int out_size, void* d_ws, size_t ws_size,
                              hipStream_t stream)
{
  const float* x   = (const float*)d_in[0];
  const float* s0  = (const float*)d_in[1];
  const float* Wi0 = (const float*)d_in[2];
  const float* Wh0 = (const float*)d_in[3];
  const float* bi0 = (const float*)d_in[4];
  const float* bh0 = (const float*)d_in[5];
  const float* Wi1 = (const float*)d_in[6];
  const float* Wh1 = (const float*)d_in[7];
  const float* bi1 = (const float*)d_in[8];
  const float* bh1 = (const float*)d_in[9];
  const float* Wfc = (const float*)d_in[10];
  const float* bfc = (const float*)d_in[11];
  float* out = (float*)d_out;
  char* ws = (char*)d_ws;

  if (ws_size < WS_NEED) return;

  hipFuncSetAttribute(reinterpret_cast<const void*>(lstm_kernel),
                      hipFuncAttributeMaxDynamicSharedMemorySize, SMEM_BYTES);

  size_t nz = 32768/8 + 2*PLANE/8;
  zero_kernel<<<(int)((nz + 255)/256), 256, 0, stream>>>(ws);
  lstm_kernel<<<NG*WPG, 256, SMEM_BYTES, stream>>>(x, s0, Wi0, Wh0, bi0, bh0,
                                                   Wi1, Wh1, bi1, bh1, Wfc, bfc,
                                                   out, ws);
}